// Round 12
// baseline (354.748 us; speedup 1.0000x reference)
//
#include <hip/hip_runtime.h>
#include <hip/hip_bf16.h>
#include <math.h>

#define L_   110
#define B_   64
#define N_   7040
#define U_   768
#define G_   512
#define H_   256
#define FF_  2048
#define EPB_ 2200
#define NC_  2816   // combined att_w(512) + wrel(2048) + root(256)

typedef __attribute__((ext_vector_type(4))) float f32x4;
typedef __attribute__((ext_vector_type(8))) short bf16x8;

__device__ __forceinline__ ushort f2b(float f) {
  union { __hip_bfloat16 h; ushort u; } cv;
  cv.h = __float2bfloat16(f);
  return cv.u;
}
__device__ __forceinline__ float b2f(ushort u) {
  union { float f; unsigned int i; } cv; cv.i = ((unsigned int)u) << 16; return cv.f;
}

// prefix(j) = number of edges with src-row j' < j within one dialogue
__device__ __forceinline__ int edge_prefix(int j) {
  if (j <= 10)  return j * 11 + (j * (j - 1)) / 2;
  if (j <= 100) return 155 + (j - 10) * 21;
  return 2045 + ((141 - j) * (j - 100)) / 2;
}

// ================= single prep kernel ======================================
// y 0..6 : f32->bf16 converts (x, in_proj, out_proj, ff1, ff2, to, clf1)
// y == 7 : flat misc (bias_comb | grelT | grootT | Wp[:,0:512] | bias2)
// y == 8 : transposes into combw (attw^T, wrel^T, root^T)
struct PrepArgs {
  const float* cin[7]; ushort* cout[7]; int n4[7];
  const float* rb; const float* grel; const float* groot;
  const float* clf1w; const float* clf1bias; const float* grelb;
  const float* attw; const float* basis; const float* comp; const float* root;
  float* bias_comb; ushort* grelrootT; ushort* Wp; float* bias2; ushort* combw;
};

__global__ __launch_bounds__(256)
void prep_kernel(PrepArgs a)
{
  __shared__ float t[32][33];
  __shared__ float cs[240];
  const int y = blockIdx.y;
  const int tid = threadIdx.x;
  if (y < 7) {
    const int n4 = a.n4[y];
    const float* __restrict__ in = a.cin[y];
    ushort* __restrict__ out = a.cout[y];
    for (int i = blockIdx.x * 256 + tid; i < n4; i += gridDim.x * 256) {
      float4 v = ((const float4*)in)[i];
      ushort4 o;
      o.x = f2b(v.x); o.y = f2b(v.y); o.z = f2b(v.z); o.w = f2b(v.w);
      ((ushort4*)out)[i] = o;
    }
  } else if (y == 7) {
    const int total = NC_ + 65536 + 65536 + 131072 + 256;
    for (int i = blockIdx.x * 256 + tid; i < total; i += gridDim.x * 256) {
      if (i < NC_) {
        a.bias_comb[i] = (i < 2560) ? 0.f : a.rb[i - 2560];
      } else if (i < NC_ + 65536) {
        const int j = i - NC_;
        const int k = j >> 8, c = j & 255;
        a.grelrootT[(size_t)c * 256 + k] = f2b(a.grel[j]);
      } else if (i < NC_ + 131072) {
        const int j = i - NC_ - 65536;
        const int k = j >> 8, c = j & 255;
        a.grelrootT[(size_t)(256 + c) * 256 + k] = f2b(a.groot[j]);
      } else if (i < NC_ + 131072 + 131072) {
        const int j = i - NC_ - 131072;
        const int o = j >> 9, c = j & 511;
        a.Wp[(size_t)o * 1024 + c] = f2b(a.clf1w[(size_t)o * 768 + c]);
      } else {
        const int tt = i - (NC_ + 131072 + 131072);
        float s = a.clf1bias[tt];
        for (int k = 0; k < 256; ++k)
          s = fmaf(a.clf1w[(size_t)tt * 768 + 512 + k], a.grelb[k], s);
        a.bias2[tt] = s;
      }
    }
  } else {
    const int tx = tid & 31, ty = tid >> 5;
    if (blockIdx.x < 256) {
      // att_w (512x512) transpose -> combw rows 0..511
      const int r0 = (blockIdx.x >> 4) * 32, c0 = (blockIdx.x & 15) * 32;
      for (int i = ty; i < 32; i += 8)
        t[i][tx] = a.attw[(size_t)(r0 + i) * 512 + c0 + tx];
      __syncthreads();
      for (int i = ty; i < 32; i += 8)
        a.combw[(size_t)(c0 + i) * 512 + r0 + tx] = f2b(t[tx][i]);
    } else if (blockIdx.x < 384) {
      const int t2 = blockIdx.x - 256;
      const int g0 = (t2 & 15) * 32, h0 = (t2 >> 4) * 32;
      if (tid < 240) cs[tid] = a.comp[tid];
      // root transpose -> combw rows 2560..2815
      for (int i = ty; i < 32; i += 8)
        t[i][tx] = a.root[(size_t)(g0 + i) * 256 + h0 + tx];
      __syncthreads();
      for (int i = ty; i < 32; i += 8)
        a.combw[(size_t)(2560 + h0 + i) * 512 + g0 + tx] = f2b(t[tx][i]);
      // wrel accumulate + transpose -> combw rows 512..2559
      float acc[8][4] = {};
      for (int bb = 0; bb < 30; ++bb) {
        const float* bp = a.basis + (size_t)bb * (G_ * H_);
#pragma unroll
        for (int k = 0; k < 4; ++k) {
          float v = bp[(size_t)(g0 + ty + 8 * k) * 256 + h0 + tx];
#pragma unroll
          for (int r = 0; r < 8; ++r) acc[r][k] = fmaf(cs[r * 30 + bb], v, acc[r][k]);
        }
      }
      for (int r = 0; r < 8; ++r) {
        __syncthreads();
#pragma unroll
        for (int k = 0; k < 4; ++k) t[ty + 8 * k][tx] = acc[r][k];
        __syncthreads();
        for (int i = ty; i < 32; i += 8)
          a.combw[(size_t)(512 + r * 256 + h0 + i) * 512 + g0 + tx] = f2b(t[tx][i]);
      }
    }
  }
}

// ===================== bf16 MFMA GEMM, 128x128 tile ========================
template<bool BIAS, bool RELU>
__global__ __launch_bounds__(256)
void mgemm_kernel(const ushort* __restrict__ A, const ushort* __restrict__ B,
                  const float* __restrict__ bias, ushort* __restrict__ Cb,
                  int K, int lda, int ldb, int ldc)
{
  __shared__ ushort sA[128 * 64];
  __shared__ ushort sB[128 * 64];
  const int tid = threadIdx.x;
  const int w = tid >> 6, l = tid & 63;

  const int gx = gridDim.x;
  const int nwg = gx * gridDim.y;
  const int lid = blockIdx.y * gx + blockIdx.x;
  const int q = nwg >> 3, r = nwg & 7;
  const int xcd = lid & 7, pos = lid >> 3;
  const int nlid = (xcd < r ? xcd * (q + 1) : r * (q + 1) + (xcd - r) * q) + pos;
  const int m0 = (nlid / gx) * 128, n0 = (nlid % gx) * 128;

  const int srow = l >> 3, sg = l & 7, rbase = w * 32;
  const int wr = w >> 1, wc = w & 1;
  const int lrow = l & 15, lk = l >> 4;
  const int xm = (l & 7) << 4;
  const int kb0 = (lk * 16) ^ xm;
  int aoff[4], boff[4];
#pragma unroll
  for (int i = 0; i < 4; ++i) {
    aoff[i] = (wr * 64 + i * 16 + lrow) * 128 + kb0;
    boff[i] = (wc * 64 + i * 16 + lrow) * 128 + kb0;
  }

  f32x4 acc[4][4];
#pragma unroll
  for (int i = 0; i < 4; ++i)
#pragma unroll
    for (int j = 0; j < 4; ++j) acc[i][j] = (f32x4){0.f, 0.f, 0.f, 0.f};

#define STAGE(k0)                                                              \
  {                                                                            \
    _Pragma("unroll")                                                          \
    for (int i = 0; i < 4; ++i) {                                              \
      const int trow = rbase + i * 8 + srow;                                   \
      const int koff = (sg * 8) ^ ((trow & 7) << 3);                           \
      const ushort* ga = A + (size_t)(m0 + trow) * lda + (k0) + koff;          \
      const ushort* gb = B + (size_t)(n0 + trow) * ldb + (k0) + koff;          \
      __builtin_amdgcn_global_load_lds(                                        \
          (const __attribute__((address_space(1))) void*)ga,                   \
          (__attribute__((address_space(3))) void*)&sA[(rbase + i * 8) * 64],  \
          16, 0, 0);                                                           \
      __builtin_amdgcn_global_load_lds(                                        \
          (const __attribute__((address_space(1))) void*)gb,                   \
          (__attribute__((address_space(3))) void*)&sB[(rbase + i * 8) * 64],  \
          16, 0, 0);                                                           \
    }                                                                          \
  }

  STAGE(0)
  for (int kt = 0;;) {
    __syncthreads();
#pragma unroll
    for (int h = 0; h < 2; ++h) {
      const int hx = h * 64;
      bf16x8 af[4], bfr[4];
#pragma unroll
      for (int i = 0; i < 4; ++i) {
        af[i]  = *(const bf16x8*)&sA[(aoff[i] ^ hx) >> 1];
        bfr[i] = *(const bf16x8*)&sB[(boff[i] ^ hx) >> 1];
      }
#pragma unroll
      for (int mi = 0; mi < 4; ++mi)
#pragma unroll
        for (int ni = 0; ni < 4; ++ni)
          acc[mi][ni] = __builtin_amdgcn_mfma_f32_16x16x32_bf16(
              af[mi], bfr[ni], acc[mi][ni], 0, 0, 0);
    }
    kt += 64;
    if (kt >= K) break;
    __syncthreads();
    STAGE(kt)
  }
#undef STAGE

  const int orow = m0 + wr * 64 + lk * 4;
  const int ocol = n0 + wc * 64 + lrow;
#pragma unroll
  for (int mi = 0; mi < 4; ++mi) {
#pragma unroll
    for (int r2 = 0; r2 < 4; ++r2) {
      const int row = orow + mi * 16 + r2;
#pragma unroll
      for (int ni = 0; ni < 4; ++ni) {
        const int col = ocol + ni * 16;
        float v = acc[mi][ni][r2];
        if constexpr (BIAS) v += bias[col];
        if constexpr (RELU) v = fmaxf(v, 0.f);
        Cb[(size_t)row * ldc + col] = f2b(v);
      }
    }
  }
}

// ===================== bf16 MFMA GEMM, 128x64 tile (narrow N) ==============
template<bool BIAS, bool RELU>
__global__ __launch_bounds__(256)
void mgemm64_kernel(const ushort* __restrict__ A, const ushort* __restrict__ B,
                    const float* __restrict__ bias, ushort* __restrict__ Cb,
                    int K, int lda, int ldb, int ldc)
{
  __shared__ ushort sA[128 * 64];
  __shared__ ushort sB[64 * 64];
  const int tid = threadIdx.x;
  const int w = tid >> 6, l = tid & 63;

  const int gx = gridDim.x;
  const int nwg = gx * gridDim.y;
  const int lid = blockIdx.y * gx + blockIdx.x;
  const int q = nwg >> 3, r = nwg & 7;
  const int xcd = lid & 7, pos = lid >> 3;
  const int nlid = (xcd < r ? xcd * (q + 1) : r * (q + 1) + (xcd - r) * q) + pos;
  const int m0 = (nlid / gx) * 128, n0 = (nlid % gx) * 64;

  const int srow = l >> 3, sg = l & 7;
  const int lrow = l & 15, lk = l >> 4;
  const int xm = (l & 7) << 4;
  const int kb0 = (lk * 16) ^ xm;
  int aoff[2], boff[4];
#pragma unroll
  for (int i = 0; i < 2; ++i) aoff[i] = (w * 32 + i * 16 + lrow) * 128 + kb0;
#pragma unroll
  for (int i = 0; i < 4; ++i) boff[i] = (i * 16 + lrow) * 128 + kb0;

  f32x4 acc[2][4];
#pragma unroll
  for (int i = 0; i < 2; ++i)
#pragma unroll
    for (int j = 0; j < 4; ++j) acc[i][j] = (f32x4){0.f, 0.f, 0.f, 0.f};

#define STAGE64(k0)                                                            \
  {                                                                            \
    _Pragma("unroll")                                                          \
    for (int i = 0; i < 4; ++i) {                                              \
      const int trow = w * 32 + i * 8 + srow;                                  \
      const int koff = (sg * 8) ^ ((trow & 7) << 3);                           \
      const ushort* ga = A + (size_t)(m0 + trow) * lda + (k0) + koff;          \
      __builtin_amdgcn_global_load_lds(                                        \
          (const __attribute__((address_space(1))) void*)ga,                   \
          (__attribute__((address_space(3))) void*)&sA[(w * 32 + i * 8) * 64], \
          16, 0, 0);                                                           \
    }                                                                          \
    _Pragma("unroll")                                                          \
    for (int i = 0; i < 2; ++i) {                                              \
      const int trow = w * 16 + i * 8 + srow;                                  \
      const int koff = (sg * 8) ^ ((trow & 7) << 3);                           \
      const ushort* gb = B + (size_t)(n0 + trow) * ldb + (k0) + koff;          \
      __builtin_amdgcn_global_load_lds(                                        \
          (const __attribute__((address_space(1))) void*)gb,                   \
          (__attribute__((address_space(3))) void*)&sB[(w * 16 + i * 8) * 64], \
          16, 0, 0);                                                           \
    }                                                                          \
  }

  STAGE64(0)
  for (int kt = 0;;) {
    __syncthreads();
#pragma unroll
    for (int h = 0; h < 2; ++h) {
      const int hx = h * 64;
      bf16x8 af[2], bfr[4];
#pragma unroll
      for (int i = 0; i < 2; ++i) af[i] = *(const bf16x8*)&sA[(aoff[i] ^ hx) >> 1];
#pragma unroll
      for (int i = 0; i < 4; ++i) bfr[i] = *(const bf16x8*)&sB[(boff[i] ^ hx) >> 1];
#pragma unroll
      for (int mi = 0; mi < 2; ++mi)
#pragma unroll
        for (int ni = 0; ni < 4; ++ni)
          acc[mi][ni] = __builtin_amdgcn_mfma_f32_16x16x32_bf16(
              af[mi], bfr[ni], acc[mi][ni], 0, 0, 0);
    }
    kt += 64;
    if (kt >= K) break;
    __syncthreads();
    STAGE64(kt)
  }
#undef STAGE64

  const int orow = m0 + w * 32 + lk * 4;
  const int ocol = n0 + lrow;
#pragma unroll
  for (int mi = 0; mi < 2; ++mi) {
#pragma unroll
    for (int r2 = 0; r2 < 4; ++r2) {
      const int row = orow + mi * 16 + r2;
#pragma unroll
      for (int ni = 0; ni < 4; ++ni) {
        const int col = ocol + ni * 16;
        float v = acc[mi][ni][r2];
        if constexpr (BIAS) v += bias[col];
        if constexpr (RELU) v = fmaxf(v, 0.f);
        Cb[(size_t)row * ldc + col] = f2b(v);
      }
    }
  }
}

// -------- V transpose (ushort2-vectorized): V(110x768) -> vt(768x128) ------
__global__ __launch_bounds__(256)
void vtrans_kernel(const ushort* __restrict__ qkvb, ushort* __restrict__ vt)
{
  __shared__ ushort t[32][34];
  const int b = blockIdx.z;
  const int r0 = blockIdx.y * 32;
  const int c0 = blockIdx.x * 32;
  const int tid = threadIdx.x;
  for (int e = tid; e < 512; e += 256) {
    const int ri = e >> 4, ci2 = (e & 15) * 2;
    ushort2 v = make_ushort2(0, 0);
    if (r0 + ri < L_)
      v = *(const ushort2*)&qkvb[((size_t)(b * L_) + r0 + ri) * 2304 + 1536 + c0 + ci2];
    t[ri][ci2] = v.x; t[ri][ci2 + 1] = v.y;
  }
  __syncthreads();
  for (int e = tid; e < 512; e += 256) {
    const int ci = e >> 4, ri2 = (e & 15) * 2;
    ushort2 o = make_ushort2(t[ri2][ci], t[ri2 + 1][ci]);
    *(ushort2*)&vt[((size_t)b * 768 + c0 + ci) * 128 + r0 + ri2] = o;
  }
}

// ====== fused attention + out_proj + residual + LayerNorm1 -> hb ===========
// 448 blocks, XCD-grouped (dialogue locality). Block = (16 q-rows, dialogue).
__global__ __launch_bounds__(256)
void attnF_kernel(const ushort* __restrict__ qkvb, const ushort* __restrict__ vt,
                  const ushort* __restrict__ xb, const ushort* __restrict__ opw,
                  const float* __restrict__ opb, const float* __restrict__ g1,
                  const float* __restrict__ b1, ushort* __restrict__ hb)
{
  const int wg = blockIdx.x;
  const int xcd = wg & 7, slot = wg >> 3;
  const int b = xcd * 8 + slot / 7;
  const int qr0 = (slot % 7) * 16;
  const int tid = threadIdx.x, w = tid >> 6, l = tid & 63;
  __shared__ float  sS[16 * 128];
  __shared__ ushort sP[16 * 128];
  __shared__ ushort sC[16][776];        // ctx bf16, pad 776 (16B-aligned rows)
  __shared__ float  sRed[16][8];
  __shared__ float  sMean[16], sRstd[16];
  const int lrow = l & 15, lq = l >> 4;

  // ---- QK^T ----
  const ushort* Qbase = qkvb + ((size_t)(b * L_) + qr0 + lrow) * 2304 + lq * 8;
  f32x4 accS[2] = {{0.f,0.f,0.f,0.f},{0.f,0.f,0.f,0.f}};
  const int nf0 = w * 2;
  for (int k0 = 0; k0 < 768; k0 += 32) {
    bf16x8 aq = *(const bf16x8*)(Qbase + k0);
#pragma unroll
    for (int f = 0; f < 2; ++f) {
      const int nf = nf0 + f;
      if (nf < 7) {
        const ushort* Kp = qkvb + ((size_t)(b * L_) + nf * 16 + lrow) * 2304
                         + 768 + k0 + lq * 8;
        bf16x8 bk = *(const bf16x8*)Kp;
        accS[f] = __builtin_amdgcn_mfma_f32_16x16x32_bf16(aq, bk, accS[f], 0, 0, 0);
      }
    }
  }
  const float scale = 0.03608439182435161f;  // 1/sqrt(768)
#pragma unroll
  for (int f = 0; f < 2; ++f) {
    const int nf = nf0 + f;
    if (nf < 7) {
#pragma unroll
      for (int r = 0; r < 4; ++r)
        sS[(lq * 4 + r) * 128 + nf * 16 + lrow] = accS[f][r] * scale;
    }
  }
  __syncthreads();

  // ---- softmax (wave w -> rows 4w..4w+3, 16 lanes/row) ----
  {
    const int row = w * 4 + lq;
    const int c0 = lrow;
    float m = -1e30f;
    for (int c = c0; c < L_; c += 16) m = fmaxf(m, sS[row * 128 + c]);
#pragma unroll
    for (int off = 8; off; off >>= 1) m = fmaxf(m, __shfl_xor(m, off));
    float pv[7];
    float sum = 0.f;
#pragma unroll
    for (int i = 0; i < 7; ++i) {
      const int c = c0 + i * 16;
      float e = (c < L_) ? __expf(sS[row * 128 + c] - m) : 0.f;
      pv[i] = e; sum += e;
    }
#pragma unroll
    for (int off = 8; off; off >>= 1) sum += __shfl_xor(sum, off);
    const float inv = 1.f / sum;
#pragma unroll
    for (int i = 0; i < 8; ++i) {
      const int c = c0 + i * 16;
      ushort pb = (i < 7 && c < L_) ? f2b(pv[i < 7 ? i : 0] * inv) : (ushort)0;
      const int g = (c >> 3) ^ (row & 7);
      sP[row * 128 + g * 8 + (c & 7)] = pb;
    }
  }
  __syncthreads();

  // ---- PV: wave w covers ctx cols [192w, 192w+192), K=128 ----
  f32x4 accO[12];
#pragma unroll
  for (int i = 0; i < 12; ++i) accO[i] = (f32x4){0.f, 0.f, 0.f, 0.f};
#pragma unroll
  for (int ks = 0; ks < 4; ++ks) {
    const int k = ks * 32 + lq * 8;
    const int g = (k >> 3) ^ (lrow & 7);
    bf16x8 ap = *(const bf16x8*)&sP[lrow * 128 + g * 8];
#pragma unroll
    for (int i = 0; i < 12; ++i) {
      const int col = w * 192 + i * 16 + lrow;
      bf16x8 bv = *(const bf16x8*)(vt + ((size_t)b * 768 + col) * 128 + k);
      accO[i] = __builtin_amdgcn_mfma_f32_16x16x32_bf16(ap, bv, accO[i], 0, 0, 0);
    }
  }
  // ctx -> LDS (bf16)
#pragma unroll
  for (int i = 0; i < 12; ++i) {
    const int col = w * 192 + i * 16 + lrow;
#pragma unroll
    for (int r = 0; r < 4; ++r)
      sC[lq * 4 + r][col] = f2b(accO[i][r]);
  }
  __syncthreads();

  // ---- out_proj: a[q][o] = sum_d ctx[q][d] * opw[o][d] ----
  f32x4 acc2[12];
#pragma unroll
  for (int i = 0; i < 12; ++i) acc2[i] = (f32x4){0.f, 0.f, 0.f, 0.f};
  for (int k0 = 0; k0 < 768; k0 += 32) {
    bf16x8 af = *(const bf16x8*)&sC[lrow][k0 + lq * 8];
#pragma unroll
    for (int i = 0; i < 12; ++i) {
      const int col = w * 192 + i * 16 + lrow;
      bf16x8 bfr = *(const bf16x8*)(opw + (size_t)col * 768 + k0 + lq * 8);
      acc2[i] = __builtin_amdgcn_mfma_f32_16x16x32_bf16(af, bfr, acc2[i], 0, 0, 0);
    }
  }

  // ---- +bias +residual, LN stats ----
  float vv[12][4];
  bool rv[4];
#pragma unroll
  for (int r = 0; r < 4; ++r) rv[r] = (qr0 + lq * 4 + r) < L_;
  float ssum[4] = {0.f, 0.f, 0.f, 0.f}, ssq[4] = {0.f, 0.f, 0.f, 0.f};
#pragma unroll
  for (int i = 0; i < 12; ++i) {
    const int col = w * 192 + i * 16 + lrow;
    const float bb = opb[col];
#pragma unroll
    for (int r = 0; r < 4; ++r) {
      float xv = 0.f;
      if (rv[r]) {
        const size_t grow = (size_t)(b * L_ + qr0 + lq * 4 + r);
        xv = b2f(xb[grow * 768 + col]);
      }
      float v = acc2[i][r] + bb + xv;
      vv[i][r] = v;
      ssum[r] += v; ssq[r] += v * v;
    }
  }
#pragma unroll
  for (int off = 1; off < 16; off <<= 1) {
#pragma unroll
    for (int r = 0; r < 4; ++r) {
      ssum[r] += __shfl_xor(ssum[r], off);
      ssq[r]  += __shfl_xor(ssq[r], off);
    }
  }
  if (lrow == 0) {
#pragma unroll
    for (int r = 0; r < 4; ++r) {
      sRed[lq * 4 + r][w] = ssum[r];
      sRed[lq * 4 + r][4 + w] = ssq[r];
    }
  }
  __syncthreads();
  if (tid < 16) {
    float S = sRed[tid][0] + sRed[tid][1] + sRed[tid][2] + sRed[tid][3];
    float Q = sRed[tid][4] + sRed[tid][5] + sRed[tid][6] + sRed[tid][7];
    float mn = S * (1.f / 768.f);
    float var = Q * (1.f / 768.f) - mn * mn;
    sMean[tid] = mn;
    sRstd[tid] = rsqrtf(var + 1e-5f);
  }
  __syncthreads();
  // ---- normalize + write hb ----
#pragma unroll
  for (int i = 0; i < 12; ++i) {
    const int col = w * 192 + i * 16 + lrow;
    const float gg = g1[col], b2 = b1[col];
#pragma unroll
    for (int r = 0; r < 4; ++r) {
      if (rv[r]) {
        const int lr = lq * 4 + r;
        const size_t grow = (size_t)(b * L_ + qr0 + lr);
        hb[grow * 768 + col] = f2b((vv[i][r] - sMean[lr]) * sRstd[lr] * gg + b2);
      }
    }
  }
}

// ------- LayerNorm(A[bf16] + Bres[bf16]) -> bf16 ---------------------------
__global__ __launch_bounds__(256)
void ln_kernel(const ushort* __restrict__ Ab, const ushort* __restrict__ Bres,
               const float* __restrict__ g, const float* __restrict__ beta,
               ushort* __restrict__ outb)
{
  const int row = blockIdx.x, tid = threadIdx.x;
  const ushort* ap = Ab + (size_t)row * U_;
  const ushort* bp = Bres + (size_t)row * U_;
  float v0 = b2f(ap[tid])       + b2f(bp[tid]);
  float v1 = b2f(ap[tid + 256]) + b2f(bp[tid + 256]);
  float v2 = b2f(ap[tid + 512]) + b2f(bp[tid + 512]);
  float s = v0 + v1 + v2, sq = v0 * v0 + v1 * v1 + v2 * v2;
  __shared__ float red[8];
#pragma unroll
  for (int off = 32; off; off >>= 1) { s += __shfl_xor(s, off); sq += __shfl_xor(sq, off); }
  const int wave = tid >> 6, lane = tid & 63;
  if (lane == 0) { red[wave] = s; red[4 + wave] = sq; }
  __syncthreads();
  if (tid == 0) {
    float ts = red[0] + red[1] + red[2] + red[3];
    float tq = red[4] + red[5] + red[6] + red[7];
    float m = ts * (1.f / 768.f);
    float var = tq * (1.f / 768.f) - m * m;
    red[0] = m; red[1] = 1.f / sqrtf(var + 1e-5f);
  }
  __syncthreads();
  const float m = red[0], inv = red[1];
  ushort* ob = outb + (size_t)row * U_;
  ob[tid]       = f2b((v0 - m) * inv * g[tid]       + beta[tid]);
  ob[tid + 256] = f2b((v1 - m) * inv * g[tid + 256] + beta[tid + 256]);
  ob[tid + 512] = f2b((v2 - m) * inv * g[tid + 512] + beta[tid + 512]);
}

// ---- graph front: {RGCN gather -> fcat2[:,768:1024] | edge softmax} -------
__global__ __launch_bounds__(256)
void graphfront_kernel(const ushort* __restrict__ combo, ushort* __restrict__ fcat2,
                       const int* __restrict__ speaker, float* __restrict__ edge_norm)
{
  const int tid = threadIdx.x;
  if (blockIdx.x < N_ / 8) {
    const int n = blockIdx.x * 8 + (tid >> 5);
    const int lane = tid & 31;
    const int b = n / L_, k = n - b * L_;
    const int j0 = max(0, k - 10), j1 = min(L_ - 1, k + 10);
    const int spk = speaker[n];
    float inv[4];
    {
      int cn[4] = {0, 0, 0, 0};
      for (int j = j0; j <= j1; ++j)
        cn[speaker[b * L_ + j] * 2 + (j >= k ? 1 : 0)]++;
#pragma unroll
      for (int q = 0; q < 4; ++q) inv[q] = cn[q] ? 1.f / (float)cn[q] : 0.f;
    }
    float acc[8] = {};
    for (int j = j0; j <= j1; ++j) {
      const int spj = speaker[b * L_ + j];
      const int c = (j >= k) ? 1 : 0;
      const int et = (spj * 2 + spk) * 2 + c;
      const float w = inv[spj * 2 + c];
      bf16x8 v = *(const bf16x8*)&combo[(size_t)(b * L_ + j) * NC_ + 512 + et * 256 + lane * 8];
#pragma unroll
      for (int i = 0; i < 8; ++i) acc[i] = fmaf(b2f((ushort)v[i]), w, acc[i]);
    }
    bf16x8 rt = *(const bf16x8*)&combo[(size_t)n * NC_ + 2560 + lane * 8];
    bf16x8 o;
#pragma unroll
    for (int i = 0; i < 8; ++i) o[i] = (short)f2b(acc[i] + b2f((ushort)rt[i]));
    *(bf16x8*)&fcat2[(size_t)n * 1024 + 768 + lane * 8] = o;
  } else {
    const int bj = blockIdx.x - N_ / 8;
    const int b = bj / L_, j = bj - b * L_;
    const int k0 = max(0, j - 10), k1 = min(L_ - 1, j + 10);
    __shared__ float s[32];
    const int wave = tid >> 6, lane = tid & 63;
    float tr[8];
    {
      bf16x8 tv = *(const bf16x8*)&combo[(size_t)bj * NC_ + lane * 8];
#pragma unroll
      for (int i = 0; i < 8; ++i) tr[i] = b2f((ushort)tv[i]);
    }
    for (int k = k0 + wave; k <= k1; k += 4) {
      bf16x8 v = *(const bf16x8*)&fcat2[(size_t)(b * L_ + k) * 1024 + lane * 8];
      float sc = 0.f;
#pragma unroll
      for (int i = 0; i < 8; ++i) sc = fmaf(b2f((ushort)v[i]), tr[i], sc);
#pragma unroll
      for (int off = 32; off; off >>= 1) sc += __shfl_xor(sc, off);
      if (lane == 0) s[k - k0] = sc;
    }
    __syncthreads();
    if (tid == 0) {
      const int W = k1 - k0 + 1;
      float m = -1e30f;
      for (int t = 0; t < W; ++t) m = fmaxf(m, s[t]);
      float sum = 0.f;
      for (int t = 0; t < W; ++t) { float e = __expf(s[t] - m); s[t] = e; sum += e; }
      const float inv = 1.f / sum;
      const int base = b * EPB_ + edge_prefix(j);
      for (int t = 0; t < W; ++t) edge_norm[base + t] = s[t] * inv;
    }
  }
}

// -------- GraphConv gather: h1 (fcat2[:,768:1024]) -> agg (fcat2[:,512:768])
__global__ __launch_bounds__(256)
void gcn_gather2_kernel(const float* __restrict__ edge_norm,
                        ushort* __restrict__ fcat2)
{
  const int tid = threadIdx.x;
  const int n = blockIdx.x * 8 + (tid >> 5);
  const int lane = tid & 31;
  const int b = n / L_, k = n - b * L_;
  const int j0 = max(0, k - 10), j1 = min(L_ - 1, k + 10);
  float acc[8] = {};
  for (int j = j0; j <= j1; ++j) {
    const float w = edge_norm[b * EPB_ + edge_prefix(j) + (k - max(0, j - 10))];
    bf16x8 v = *(const bf16x8*)&fcat2[(size_t)(b * L_ + j) * 1024 + 768 + lane * 8];
#pragma unroll
    for (int i = 0; i < 8; ++i) acc[i] = fmaf(b2f((ushort)v[i]), w, acc[i]);
  }
  bf16x8 o;
#pragma unroll
  for (int i = 0; i < 8; ++i) o[i] = (short)f2b(acc[i]);
  *(bf16x8*)&fcat2[(size_t)n * 1024 + 512 + lane * 8] = o;
}

// ------------- final tiny GEMM: out = hid(bf16) @ clf2_w^T + clf2_b --------
__global__ __launch_bounds__(256)
void clf2_kernel(const ushort* __restrict__ hid, const float* __restrict__ w,
                 const float* __restrict__ bias, float* __restrict__ out)
{
  __shared__ float wsm[7 * H_];
  const int tid = threadIdx.x;
  for (int i = tid; i < 7 * H_; i += 256) wsm[i] = w[i];
  __syncthreads();
  const int idx = blockIdx.x * 256 + threadIdx.x;
  if (idx < N_ * 7) {
    const int n = idx / 7, t = idx - n * 7;
    const ushort* hp = hid + (size_t)n * H_;
    const float* wp = wsm + t * H_;
    float acc = bias[t];
    for (int d0 = 0; d0 < H_; d0 += 8) {
      bf16x8 v = *(const bf16x8*)(hp + d0);
#pragma unroll
      for (int i = 0; i < 8; ++i) acc = fmaf(b2f((ushort)v[i]), wp[d0 + i], acc);
    }
    out[idx] = acc;
  }
}

extern "C" void kernel_launch(void* const* d_in, const int* in_sizes, int n_in,
                              void* d_out, int out_size, void* d_ws, size_t ws_size,
                              hipStream_t stream)
{
  const float* x          = (const float*)d_in[0];
  const float* in_proj_w  = (const float*)d_in[1];
  const float* in_proj_b  = (const float*)d_in[2];
  const float* out_proj_w = (const float*)d_in[3];
  const float* out_proj_b = (const float*)d_in[4];
  const float* ln1_g      = (const float*)d_in[5];
  const float* ln1_b      = (const float*)d_in[6];
  const float* ff1_w      = (const float*)d_in[7];
  const float* ff1_b      = (const float*)d_in[8];
  const float* ff2_w      = (const float*)d_in[9];
  const float* ff2_b      = (const float*)d_in[10];
  const float* ln2_g      = (const float*)d_in[11];
  const float* ln2_b      = (const float*)d_in[12];
  const float* to_w       = (const float*)d_in[13];
  const float* to_b       = (const float*)d_in[14];
  const float* att_w      = (const float*)d_in[15];
  const float* rgcn_basis = (const float*)d_in[16];
  const float* rgcn_comp  = (const float*)d_in[17];
  const float* rgcn_root  = (const float*)d_in[18];
  const float* rgcn_bias  = (const float*)d_in[19];
  const float* gc_rel_w   = (const float*)d_in[20];
  const float* gc_rel_b   = (const float*)d_in[21];
  const float* gc_root_w  = (const float*)d_in[22];
  const float* clf1_w     = (const float*)d_in[23];
  const float* clf1_b     = (const float*)d_in[24];
  const float* clf2_w     = (const float*)d_in[25];
  const float* clf2_b     = (const float*)d_in[26];
  const int*   speaker    = (const int*)d_in[27];
  float* out = (float*)d_out;
  char* p = (char*)d_ws;

  // ---- workspace regions ----
  // R1 (65MB): qkvb bf16 -> ff bf16 -> combo bf16 (N x 2816)
  ushort* R1b    = (ushort*)p;
  p += (size_t)N_ * 2304 * 4;
  // R2 (21.6MB): ffoB bf16 ; tail: edge_norm f32
  ushort* ffoB   = (ushort*)p;
  float*  en     = (float*)(p + (size_t)N_ * 512 * 4);
  p += (size_t)N_ * 768 * 4;
  // R3 (21.6MB): vt bf16 (attn) -> hidB bf16
  ushort* vt    = (ushort*)p;
  ushort* hidB  = (ushort*)p;
  p += (size_t)N_ * 768 * 4;
  // R4 (10.8MB): xb
  ushort* xb    = (ushort*)p;
  p += (size_t)N_ * 768 * 2;
  // R5 (10.8MB): hb bf16
  ushort* hb    = (ushort*)p;
  p += (size_t)N_ * 768 * 2;
  // R6 (14.4MB): fcat2 bf16 (N x 1024: [feats | agg | h1])
  ushort* fcat2 = (ushort*)p;
  p += (size_t)N_ * 1024 * 2;
  // weights
  ushort* in_projb = (ushort*)p; p += (size_t)2304 * 768 * 2;
  ushort* out_projb= (ushort*)p; p += (size_t)768 * 768 * 2;
  ushort* ff1b     = (ushort*)p; p += (size_t)2048 * 768 * 2;
  ushort* ff2b     = (ushort*)p; p += (size_t)768 * 2048 * 2;
  ushort* tob      = (ushort*)p; p += (size_t)512 * 768 * 2;
  ushort* combw    = (ushort*)p; p += (size_t)NC_ * 512 * 2;
  ushort* clf1b16  = (ushort*)p; p += (size_t)256 * 768 * 2;
  ushort* Wp       = (ushort*)p; p += (size_t)256 * 1024 * 2;   // [W1a|Wc|Wd]
  ushort* grelrootT= (ushort*)p; p += (size_t)512 * 256 * 2;    // [gc_rel^T; gc_root^T]
  float*  bias_comb= (float*)p;  p += NC_ * 4;
  float*  bias2    = (float*)p;  p += 256 * 4;

  // ---- prep (1 dispatch) + Wcd GEMM ----
  PrepArgs pa;
  pa.cin[0] = x;          pa.cout[0] = xb;        pa.n4[0] = N_ * 768 / 4;
  pa.cin[1] = in_proj_w;  pa.cout[1] = in_projb;  pa.n4[1] = 2304 * 768 / 4;
  pa.cin[2] = out_proj_w; pa.cout[2] = out_projb; pa.n4[2] = 768 * 768 / 4;
  pa.cin[3] = ff1_w;      pa.cout[3] = ff1b;      pa.n4[3] = 2048 * 768 / 4;
  pa.cin[4] = ff2_w;      pa.cout[4] = ff2b;      pa.n4[4] = 768 * 2048 / 4;
  pa.cin[5] = to_w;       pa.cout[5] = tob;       pa.n4[5] = 512 * 768 / 4;
  pa.cin[6] = clf1_w;     pa.cout[6] = clf1b16;   pa.n4[6] = 256 * 768 / 4;
  pa.rb = rgcn_bias; pa.grel = gc_rel_w; pa.groot = gc_root_w;
  pa.clf1w = clf1_w; pa.clf1bias = clf1_b; pa.grelb = gc_rel_b;
  pa.attw = att_w; pa.basis = rgcn_basis; pa.comp = rgcn_comp; pa.root = rgcn_root;
  pa.bias_comb = bias_comb; pa.grelrootT = grelrootT; pa.Wp = Wp;
  pa.bias2 = bias2; pa.combw = combw;
  prep_kernel<<<dim3(768, 9), 256, 0, stream>>>(pa);
  // Wp[:,512:1024] = clf1[:,512:768] @ [gc_rel^T; gc_root^T]^T
  mgemm64_kernel<false, false><<<dim3(8, 2), 256, 0, stream>>>(
      clf1b16 + 512, grelrootT, nullptr, Wp + 512, 256, 768, 256, 1024);

  // ---- main pipeline ----
  // qkvb = bf16(x @ in_proj^T + b)
  mgemm_kernel<true, false><<<dim3(18, 55), 256, 0, stream>>>(
      xb, in_projb, in_proj_b, R1b, 768, 768, 768, 2304);
  vtrans_kernel<<<dim3(24, 4, 64), 256, 0, stream>>>(R1b, vt);
  // attention + out_proj + residual + LN1 -> hb
  attnF_kernel<<<448, 256, 0, stream>>>(R1b, vt, xb, out_projb, out_proj_b,
                                        ln1_g, ln1_b, hb);
  // ff = relu(h @ ff1^T + b)
  mgemm_kernel<true, true><<<dim3(16, 55), 256, 0, stream>>>(
      hb, ff1b, ff1_b, R1b, 768, 768, 768, 2048);
  // ffoB = bf16(ff @ ff2^T + b)
  mgemm64_kernel<true, false><<<dim3(12, 55), 256, 0, stream>>>(
      R1b, ff2b, ff2_b, ffoB, 2048, 2048, 2048, 768);
  ln_kernel<<<N_, 256, 0, stream>>>(hb, ffoB, ln2_g, ln2_b, hb);
  // feats -> fcat2[:, 0:512]  (ldc = 1024)
  mgemm64_kernel<true, false><<<dim3(8, 55), 256, 0, stream>>>(
      hb, tob, to_b, fcat2, 768, 768, 768, 1024);
  // combo = bf16(feats @ [attw_t|wrel_t|root_t]^T + bias_comb)  (lda = 1024)
  mgemm_kernel<true, false><<<dim3(22, 55), 256, 0, stream>>>(
      fcat2, combw, bias_comb, R1b, 512, 1024, 512, NC_);
  graphfront_kernel<<<N_ / 8 + N_, 256, 0, stream>>>(R1b, fcat2, speaker, en);
  gcn_gather2_kernel<<<N_ / 8, 256, 0, stream>>>(en, fcat2);
  // hid = relu([feats|agg|h1] @ [W1a|Wc|Wd]^T + bias2)   (K = 1024)
  mgemm64_kernel<true, true><<<dim3(4, 55), 256, 0, stream>>>(
      fcat2, Wp, bias2, hidB, 1024, 1024, 1024, 256);
  clf2_kernel<<<(N_ * 7 + 255) / 256, 256, 0, stream>>>(hidB, clf2_w, clf2_b, out);
}

// Round 13
// 302.517 us; speedup vs baseline: 1.1727x; 1.1727x over previous
//
#include <hip/hip_runtime.h>
#include <hip/hip_bf16.h>
#include <math.h>

#define L_   110
#define B_   64
#define N_   7040
#define U_   768
#define G_   512
#define H_   256
#define FF_  2048
#define EPB_ 2200
#define NC_  2816   // combined att_w(512) + wrel(2048) + root(256)

typedef __attribute__((ext_vector_type(4))) float f32x4;
typedef __attribute__((ext_vector_type(8))) short bf16x8;

__device__ __forceinline__ ushort f2b(float f) {
  union { __hip_bfloat16 h; ushort u; } cv;
  cv.h = __float2bfloat16(f);
  return cv.u;
}
__device__ __forceinline__ float b2f(ushort u) {
  union { float f; unsigned int i; } cv; cv.i = ((unsigned int)u) << 16; return cv.f;
}

// prefix(j) = number of edges with src-row j' < j within one dialogue
__device__ __forceinline__ int edge_prefix(int j) {
  if (j <= 10)  return j * 11 + (j * (j - 1)) / 2;
  if (j <= 100) return 155 + (j - 10) * 21;
  return 2045 + ((141 - j) * (j - 100)) / 2;
}

// ================= single prep kernel ======================================
struct PrepArgs {
  const float* cin[7]; ushort* cout[7]; int n4[7];
  const float* rb; const float* grel; const float* groot;
  const float* clf1w; const float* clf1bias; const float* grelb;
  const float* attw; const float* basis; const float* comp; const float* root;
  float* bias_comb; ushort* grelrootT; ushort* Wp; float* bias2; ushort* combw;
};

__global__ __launch_bounds__(256)
void prep_kernel(PrepArgs a)
{
  __shared__ float t[32][33];
  __shared__ float cs[240];
  const int y = blockIdx.y;
  const int tid = threadIdx.x;
  if (y < 7) {
    const int n4 = a.n4[y];
    const float* __restrict__ in = a.cin[y];
    ushort* __restrict__ out = a.cout[y];
    for (int i = blockIdx.x * 256 + tid; i < n4; i += gridDim.x * 256) {
      float4 v = ((const float4*)in)[i];
      ushort4 o;
      o.x = f2b(v.x); o.y = f2b(v.y); o.z = f2b(v.z); o.w = f2b(v.w);
      ((ushort4*)out)[i] = o;
    }
  } else if (y == 7) {
    const int total = NC_ + 65536 + 65536 + 131072 + 256;
    for (int i = blockIdx.x * 256 + tid; i < total; i += gridDim.x * 256) {
      if (i < NC_) {
        a.bias_comb[i] = (i < 2560) ? 0.f : a.rb[i - 2560];
      } else if (i < NC_ + 65536) {
        const int j = i - NC_;
        const int k = j >> 8, c = j & 255;
        a.grelrootT[(size_t)c * 256 + k] = f2b(a.grel[j]);
      } else if (i < NC_ + 131072) {
        const int j = i - NC_ - 65536;
        const int k = j >> 8, c = j & 255;
        a.grelrootT[(size_t)(256 + c) * 256 + k] = f2b(a.groot[j]);
      } else if (i < NC_ + 131072 + 131072) {
        const int j = i - NC_ - 131072;
        const int o = j >> 9, c = j & 511;
        a.Wp[(size_t)o * 1024 + c] = f2b(a.clf1w[(size_t)o * 768 + c]);
      } else {
        const int tt = i - (NC_ + 131072 + 131072);
        float s = a.clf1bias[tt];
        for (int k = 0; k < 256; ++k)
          s = fmaf(a.clf1w[(size_t)tt * 768 + 512 + k], a.grelb[k], s);
        a.bias2[tt] = s;
      }
    }
  } else {
    const int tx = tid & 31, ty = tid >> 5;
    if (blockIdx.x < 256) {
      const int r0 = (blockIdx.x >> 4) * 32, c0 = (blockIdx.x & 15) * 32;
      for (int i = ty; i < 32; i += 8)
        t[i][tx] = a.attw[(size_t)(r0 + i) * 512 + c0 + tx];
      __syncthreads();
      for (int i = ty; i < 32; i += 8)
        a.combw[(size_t)(c0 + i) * 512 + r0 + tx] = f2b(t[tx][i]);
    } else if (blockIdx.x < 384) {
      const int t2 = blockIdx.x - 256;
      const int g0 = (t2 & 15) * 32, h0 = (t2 >> 4) * 32;
      if (tid < 240) cs[tid] = a.comp[tid];
      for (int i = ty; i < 32; i += 8)
        t[i][tx] = a.root[(size_t)(g0 + i) * 256 + h0 + tx];
      __syncthreads();
      for (int i = ty; i < 32; i += 8)
        a.combw[(size_t)(2560 + h0 + i) * 512 + g0 + tx] = f2b(t[tx][i]);
      float acc[8][4] = {};
      for (int bb = 0; bb < 30; ++bb) {
        const float* bp = a.basis + (size_t)bb * (G_ * H_);
#pragma unroll
        for (int k = 0; k < 4; ++k) {
          float v = bp[(size_t)(g0 + ty + 8 * k) * 256 + h0 + tx];
#pragma unroll
          for (int r = 0; r < 8; ++r) acc[r][k] = fmaf(cs[r * 30 + bb], v, acc[r][k]);
        }
      }
      for (int r = 0; r < 8; ++r) {
        __syncthreads();
#pragma unroll
        for (int k = 0; k < 4; ++k) t[ty + 8 * k][tx] = acc[r][k];
        __syncthreads();
        for (int i = ty; i < 32; i += 8)
          a.combw[(size_t)(512 + r * 256 + h0 + i) * 512 + g0 + tx] = f2b(t[tx][i]);
      }
    }
  }
}

// ===================== bf16 MFMA GEMM, 128x128 tile ========================
template<bool BIAS, bool RELU>
__global__ __launch_bounds__(256)
void mgemm_kernel(const ushort* __restrict__ A, const ushort* __restrict__ B,
                  const float* __restrict__ bias, ushort* __restrict__ Cb,
                  int K, int lda, int ldb, int ldc)
{
  __shared__ ushort sA[128 * 64];
  __shared__ ushort sB[128 * 64];
  const int tid = threadIdx.x;
  const int w = tid >> 6, l = tid & 63;

  const int gx = gridDim.x;
  const int nwg = gx * gridDim.y;
  const int lid = blockIdx.y * gx + blockIdx.x;
  const int q = nwg >> 3, r = nwg & 7;
  const int xcd = lid & 7, pos = lid >> 3;
  const int nlid = (xcd < r ? xcd * (q + 1) : r * (q + 1) + (xcd - r) * q) + pos;
  const int m0 = (nlid / gx) * 128, n0 = (nlid % gx) * 128;

  const int srow = l >> 3, sg = l & 7, rbase = w * 32;
  const int wr = w >> 1, wc = w & 1;
  const int lrow = l & 15, lk = l >> 4;
  const int xm = (l & 7) << 4;
  const int kb0 = (lk * 16) ^ xm;
  int aoff[4], boff[4];
#pragma unroll
  for (int i = 0; i < 4; ++i) {
    aoff[i] = (wr * 64 + i * 16 + lrow) * 128 + kb0;
    boff[i] = (wc * 64 + i * 16 + lrow) * 128 + kb0;
  }

  f32x4 acc[4][4];
#pragma unroll
  for (int i = 0; i < 4; ++i)
#pragma unroll
    for (int j = 0; j < 4; ++j) acc[i][j] = (f32x4){0.f, 0.f, 0.f, 0.f};

#define STAGE(k0)                                                              \
  {                                                                            \
    _Pragma("unroll")                                                          \
    for (int i = 0; i < 4; ++i) {                                              \
      const int trow = rbase + i * 8 + srow;                                   \
      const int koff = (sg * 8) ^ ((trow & 7) << 3);                           \
      const ushort* ga = A + (size_t)(m0 + trow) * lda + (k0) + koff;          \
      const ushort* gb = B + (size_t)(n0 + trow) * ldb + (k0) + koff;          \
      __builtin_amdgcn_global_load_lds(                                        \
          (const __attribute__((address_space(1))) void*)ga,                   \
          (__attribute__((address_space(3))) void*)&sA[(rbase + i * 8) * 64],  \
          16, 0, 0);                                                           \
      __builtin_amdgcn_global_load_lds(                                        \
          (const __attribute__((address_space(1))) void*)gb,                   \
          (__attribute__((address_space(3))) void*)&sB[(rbase + i * 8) * 64],  \
          16, 0, 0);                                                           \
    }                                                                          \
  }

  STAGE(0)
  for (int kt = 0;;) {
    __syncthreads();
#pragma unroll
    for (int h = 0; h < 2; ++h) {
      const int hx = h * 64;
      bf16x8 af[4], bfr[4];
#pragma unroll
      for (int i = 0; i < 4; ++i) {
        af[i]  = *(const bf16x8*)&sA[(aoff[i] ^ hx) >> 1];
        bfr[i] = *(const bf16x8*)&sB[(boff[i] ^ hx) >> 1];
      }
#pragma unroll
      for (int mi = 0; mi < 4; ++mi)
#pragma unroll
        for (int ni = 0; ni < 4; ++ni)
          acc[mi][ni] = __builtin_amdgcn_mfma_f32_16x16x32_bf16(
              af[mi], bfr[ni], acc[mi][ni], 0, 0, 0);
    }
    kt += 64;
    if (kt >= K) break;
    __syncthreads();
    STAGE(kt)
  }
#undef STAGE

  const int orow = m0 + wr * 64 + lk * 4;
  const int ocol = n0 + wc * 64 + lrow;
#pragma unroll
  for (int mi = 0; mi < 4; ++mi) {
#pragma unroll
    for (int r2 = 0; r2 < 4; ++r2) {
      const int row = orow + mi * 16 + r2;
#pragma unroll
      for (int ni = 0; ni < 4; ++ni) {
        const int col = ocol + ni * 16;
        float v = acc[mi][ni][r2];
        if constexpr (BIAS) v += bias[col];
        if constexpr (RELU) v = fmaxf(v, 0.f);
        Cb[(size_t)row * ldc + col] = f2b(v);
      }
    }
  }
}

// ===================== bf16 MFMA GEMM, 128x64 tile (narrow N) ==============
template<bool BIAS, bool RELU>
__global__ __launch_bounds__(256)
void mgemm64_kernel(const ushort* __restrict__ A, const ushort* __restrict__ B,
                    const float* __restrict__ bias, ushort* __restrict__ Cb,
                    int K, int lda, int ldb, int ldc)
{
  __shared__ ushort sA[128 * 64];
  __shared__ ushort sB[64 * 64];
  const int tid = threadIdx.x;
  const int w = tid >> 6, l = tid & 63;

  const int gx = gridDim.x;
  const int nwg = gx * gridDim.y;
  const int lid = blockIdx.y * gx + blockIdx.x;
  const int q = nwg >> 3, r = nwg & 7;
  const int xcd = lid & 7, pos = lid >> 3;
  const int nlid = (xcd < r ? xcd * (q + 1) : r * (q + 1) + (xcd - r) * q) + pos;
  const int m0 = (nlid / gx) * 128, n0 = (nlid % gx) * 64;

  const int srow = l >> 3, sg = l & 7;
  const int lrow = l & 15, lk = l >> 4;
  const int xm = (l & 7) << 4;
  const int kb0 = (lk * 16) ^ xm;
  int aoff[2], boff[4];
#pragma unroll
  for (int i = 0; i < 2; ++i) aoff[i] = (w * 32 + i * 16 + lrow) * 128 + kb0;
#pragma unroll
  for (int i = 0; i < 4; ++i) boff[i] = (i * 16 + lrow) * 128 + kb0;

  f32x4 acc[2][4];
#pragma unroll
  for (int i = 0; i < 2; ++i)
#pragma unroll
    for (int j = 0; j < 4; ++j) acc[i][j] = (f32x4){0.f, 0.f, 0.f, 0.f};

#define STAGE64(k0)                                                            \
  {                                                                            \
    _Pragma("unroll")                                                          \
    for (int i = 0; i < 4; ++i) {                                              \
      const int trow = w * 32 + i * 8 + srow;                                  \
      const int koff = (sg * 8) ^ ((trow & 7) << 3);                           \
      const ushort* ga = A + (size_t)(m0 + trow) * lda + (k0) + koff;          \
      __builtin_amdgcn_global_load_lds(                                        \
          (const __attribute__((address_space(1))) void*)ga,                   \
          (__attribute__((address_space(3))) void*)&sA[(w * 32 + i * 8) * 64], \
          16, 0, 0);                                                           \
    }                                                                          \
    _Pragma("unroll")                                                          \
    for (int i = 0; i < 2; ++i) {                                              \
      const int trow = w * 16 + i * 8 + srow;                                  \
      const int koff = (sg * 8) ^ ((trow & 7) << 3);                           \
      const ushort* gb = B + (size_t)(n0 + trow) * ldb + (k0) + koff;          \
      __builtin_amdgcn_global_load_lds(                                        \
          (const __attribute__((address_space(1))) void*)gb,                   \
          (__attribute__((address_space(3))) void*)&sB[(w * 16 + i * 8) * 64], \
          16, 0, 0);                                                           \
    }                                                                          \
  }

  STAGE64(0)
  for (int kt = 0;;) {
    __syncthreads();
#pragma unroll
    for (int h = 0; h < 2; ++h) {
      const int hx = h * 64;
      bf16x8 af[2], bfr[4];
#pragma unroll
      for (int i = 0; i < 2; ++i) af[i] = *(const bf16x8*)&sA[(aoff[i] ^ hx) >> 1];
#pragma unroll
      for (int i = 0; i < 4; ++i) bfr[i] = *(const bf16x8*)&sB[(boff[i] ^ hx) >> 1];
#pragma unroll
      for (int mi = 0; mi < 2; ++mi)
#pragma unroll
        for (int ni = 0; ni < 4; ++ni)
          acc[mi][ni] = __builtin_amdgcn_mfma_f32_16x16x32_bf16(
              af[mi], bfr[ni], acc[mi][ni], 0, 0, 0);
    }
    kt += 64;
    if (kt >= K) break;
    __syncthreads();
    STAGE64(kt)
  }
#undef STAGE64

  const int orow = m0 + w * 32 + lk * 4;
  const int ocol = n0 + lrow;
#pragma unroll
  for (int mi = 0; mi < 2; ++mi) {
#pragma unroll
    for (int r2 = 0; r2 < 4; ++r2) {
      const int row = orow + mi * 16 + r2;
#pragma unroll
      for (int ni = 0; ni < 4; ++ni) {
        const int col = ocol + ni * 16;
        float v = acc[mi][ni][r2];
        if constexpr (BIAS) v += bias[col];
        if constexpr (RELU) v = fmaxf(v, 0.f);
        Cb[(size_t)row * ldc + col] = f2b(v);
      }
    }
  }
}

// -------- V transpose (ushort2-vectorized): V(110x768) -> vt(768x128) ------
__global__ __launch_bounds__(256)
void vtrans_kernel(const ushort* __restrict__ qkvb, ushort* __restrict__ vt)
{
  __shared__ ushort t[32][34];
  const int b = blockIdx.z;
  const int r0 = blockIdx.y * 32;
  const int c0 = blockIdx.x * 32;
  const int tid = threadIdx.x;
  for (int e = tid; e < 512; e += 256) {
    const int ri = e >> 4, ci2 = (e & 15) * 2;
    ushort2 v = make_ushort2(0, 0);
    if (r0 + ri < L_)
      v = *(const ushort2*)&qkvb[((size_t)(b * L_) + r0 + ri) * 2304 + 1536 + c0 + ci2];
    t[ri][ci2] = v.x; t[ri][ci2 + 1] = v.y;
  }
  __syncthreads();
  for (int e = tid; e < 512; e += 256) {
    const int ci = e >> 4, ri2 = (e & 15) * 2;
    ushort2 o = make_ushort2(t[ri2][ci], t[ri2 + 1][ci]);
    *(ushort2*)&vt[((size_t)b * 768 + c0 + ci) * 128 + r0 + ri2] = o;
  }
}

// -------- MFMA attention: 448 blocks, XCD-grouped ------------------------
__global__ __launch_bounds__(256)
void attnM_kernel(const ushort* __restrict__ qkvb, const ushort* __restrict__ vt,
                  ushort* __restrict__ ctxb)
{
  const int wg = blockIdx.x;
  const int xcd = wg & 7, slot = wg >> 3;
  const int b = xcd * 8 + slot / 7;
  const int qr0 = (slot % 7) * 16;
  const int tid = threadIdx.x, w = tid >> 6, l = tid & 63;
  __shared__ float  sS[16 * 128];
  __shared__ ushort sP[16 * 128];
  const int lrow = l & 15, lq = l >> 4;

  const ushort* Qbase = qkvb + ((size_t)(b * L_) + qr0 + lrow) * 2304 + lq * 8;
  f32x4 accS[2] = {{0.f,0.f,0.f,0.f},{0.f,0.f,0.f,0.f}};
  const int nf0 = w * 2;
  for (int k0 = 0; k0 < 768; k0 += 32) {
    bf16x8 aq = *(const bf16x8*)(Qbase + k0);
#pragma unroll
    for (int f = 0; f < 2; ++f) {
      const int nf = nf0 + f;
      if (nf < 7) {
        const ushort* Kp = qkvb + ((size_t)(b * L_) + nf * 16 + lrow) * 2304
                         + 768 + k0 + lq * 8;
        bf16x8 bk = *(const bf16x8*)Kp;
        accS[f] = __builtin_amdgcn_mfma_f32_16x16x32_bf16(aq, bk, accS[f], 0, 0, 0);
      }
    }
  }
  const float scale = 0.03608439182435161f;  // 1/sqrt(768)
#pragma unroll
  for (int f = 0; f < 2; ++f) {
    const int nf = nf0 + f;
    if (nf < 7) {
#pragma unroll
      for (int r = 0; r < 4; ++r)
        sS[(lq * 4 + r) * 128 + nf * 16 + lrow] = accS[f][r] * scale;
    }
  }
  __syncthreads();

  {
    const int row = w * 4 + lq;
    const int c0 = lrow;
    float m = -1e30f;
    for (int c = c0; c < L_; c += 16) m = fmaxf(m, sS[row * 128 + c]);
#pragma unroll
    for (int off = 8; off; off >>= 1) m = fmaxf(m, __shfl_xor(m, off));
    float pv[7];
    float sum = 0.f;
#pragma unroll
    for (int i = 0; i < 7; ++i) {
      const int c = c0 + i * 16;
      float e = (c < L_) ? __expf(sS[row * 128 + c] - m) : 0.f;
      pv[i] = e; sum += e;
    }
#pragma unroll
    for (int off = 8; off; off >>= 1) sum += __shfl_xor(sum, off);
    const float inv = 1.f / sum;
#pragma unroll
    for (int i = 0; i < 8; ++i) {
      const int c = c0 + i * 16;
      ushort pb = (i < 7 && c < L_) ? f2b(pv[i < 7 ? i : 0] * inv) : (ushort)0;
      const int g = (c >> 3) ^ (row & 7);
      sP[row * 128 + g * 8 + (c & 7)] = pb;
    }
  }
  __syncthreads();

  f32x4 accO[12];
#pragma unroll
  for (int i = 0; i < 12; ++i) accO[i] = (f32x4){0.f, 0.f, 0.f, 0.f};
#pragma unroll
  for (int ks = 0; ks < 4; ++ks) {
    const int k = ks * 32 + lq * 8;
    const int g = (k >> 3) ^ (lrow & 7);
    bf16x8 ap = *(const bf16x8*)&sP[lrow * 128 + g * 8];
#pragma unroll
    for (int i = 0; i < 12; ++i) {
      const int col = w * 192 + i * 16 + lrow;
      bf16x8 bv = *(const bf16x8*)(vt + ((size_t)b * 768 + col) * 128 + k);
      accO[i] = __builtin_amdgcn_mfma_f32_16x16x32_bf16(ap, bv, accO[i], 0, 0, 0);
    }
  }
#pragma unroll
  for (int i = 0; i < 12; ++i) {
    const int col = w * 192 + i * 16 + lrow;
#pragma unroll
    for (int r = 0; r < 4; ++r) {
      const int row = qr0 + lq * 4 + r;
      if (row < L_)
        ctxb[((size_t)b * L_ + row) * 768 + col] = f2b(accO[i][r]);
    }
  }
}

// ------- LayerNorm(A[bf16] + Bres[bf16]) -> bf16 ---------------------------
__global__ __launch_bounds__(256)
void ln_kernel(const ushort* __restrict__ Ab, const ushort* __restrict__ Bres,
               const float* __restrict__ g, const float* __restrict__ beta,
               ushort* __restrict__ outb)
{
  const int row = blockIdx.x, tid = threadIdx.x;
  const ushort* ap = Ab + (size_t)row * U_;
  const ushort* bp = Bres + (size_t)row * U_;
  float v0 = b2f(ap[tid])       + b2f(bp[tid]);
  float v1 = b2f(ap[tid + 256]) + b2f(bp[tid + 256]);
  float v2 = b2f(ap[tid + 512]) + b2f(bp[tid + 512]);
  float s = v0 + v1 + v2, sq = v0 * v0 + v1 * v1 + v2 * v2;
  __shared__ float red[8];
#pragma unroll
  for (int off = 32; off; off >>= 1) { s += __shfl_xor(s, off); sq += __shfl_xor(sq, off); }
  const int wave = tid >> 6, lane = tid & 63;
  if (lane == 0) { red[wave] = s; red[4 + wave] = sq; }
  __syncthreads();
  if (tid == 0) {
    float ts = red[0] + red[1] + red[2] + red[3];
    float tq = red[4] + red[5] + red[6] + red[7];
    float m = ts * (1.f / 768.f);
    float var = tq * (1.f / 768.f) - m * m;
    red[0] = m; red[1] = 1.f / sqrtf(var + 1e-5f);
  }
  __syncthreads();
  const float m = red[0], inv = red[1];
  ushort* ob = outb + (size_t)row * U_;
  ob[tid]       = f2b((v0 - m) * inv * g[tid]       + beta[tid]);
  ob[tid + 256] = f2b((v1 - m) * inv * g[tid + 256] + beta[tid + 256]);
  ob[tid + 512] = f2b((v2 - m) * inv * g[tid + 512] + beta[tid + 512]);
}

// ---- graph front: {RGCN gather -> fcat2[:,768:1024] | edge softmax} -------
__global__ __launch_bounds__(256)
void graphfront_kernel(const ushort* __restrict__ combo, ushort* __restrict__ fcat2,
                       const int* __restrict__ speaker, float* __restrict__ edge_norm)
{
  const int tid = threadIdx.x;
  if (blockIdx.x < N_ / 8) {
    const int n = blockIdx.x * 8 + (tid >> 5);
    const int lane = tid & 31;
    const int b = n / L_, k = n - b * L_;
    const int j0 = max(0, k - 10), j1 = min(L_ - 1, k + 10);
    const int spk = speaker[n];
    float inv[4];
    {
      int cn[4] = {0, 0, 0, 0};
      for (int j = j0; j <= j1; ++j)
        cn[speaker[b * L_ + j] * 2 + (j >= k ? 1 : 0)]++;
#pragma unroll
      for (int q = 0; q < 4; ++q) inv[q] = cn[q] ? 1.f / (float)cn[q] : 0.f;
    }
    float acc[8] = {};
    for (int j = j0; j <= j1; ++j) {
      const int spj = speaker[b * L_ + j];
      const int c = (j >= k) ? 1 : 0;
      const int et = (spj * 2 + spk) * 2 + c;
      const float w = inv[spj * 2 + c];
      bf16x8 v = *(const bf16x8*)&combo[(size_t)(b * L_ + j) * NC_ + 512 + et * 256 + lane * 8];
#pragma unroll
      for (int i = 0; i < 8; ++i) acc[i] = fmaf(b2f((ushort)v[i]), w, acc[i]);
    }
    bf16x8 rt = *(const bf16x8*)&combo[(size_t)n * NC_ + 2560 + lane * 8];
    bf16x8 o;
#pragma unroll
    for (int i = 0; i < 8; ++i) o[i] = (short)f2b(acc[i] + b2f((ushort)rt[i]));
    *(bf16x8*)&fcat2[(size_t)n * 1024 + 768 + lane * 8] = o;
  } else {
    const int bj = blockIdx.x - N_ / 8;
    const int b = bj / L_, j = bj - b * L_;
    const int k0 = max(0, j - 10), k1 = min(L_ - 1, j + 10);
    __shared__ float s[32];
    const int wave = tid >> 6, lane = tid & 63;
    float tr[8];
    {
      bf16x8 tv = *(const bf16x8*)&combo[(size_t)bj * NC_ + lane * 8];
#pragma unroll
      for (int i = 0; i < 8; ++i) tr[i] = b2f((ushort)tv[i]);
    }
    for (int k = k0 + wave; k <= k1; k += 4) {
      bf16x8 v = *(const bf16x8*)&fcat2[(size_t)(b * L_ + k) * 1024 + lane * 8];
      float sc = 0.f;
#pragma unroll
      for (int i = 0; i < 8; ++i) sc = fmaf(b2f((ushort)v[i]), tr[i], sc);
#pragma unroll
      for (int off = 32; off; off >>= 1) sc += __shfl_xor(sc, off);
      if (lane == 0) s[k - k0] = sc;
    }
    __syncthreads();
    if (tid == 0) {
      const int W = k1 - k0 + 1;
      float m = -1e30f;
      for (int t = 0; t < W; ++t) m = fmaxf(m, s[t]);
      float sum = 0.f;
      for (int t = 0; t < W; ++t) { float e = __expf(s[t] - m); s[t] = e; sum += e; }
      const float inv = 1.f / sum;
      const int base = b * EPB_ + edge_prefix(j);
      for (int t = 0; t < W; ++t) edge_norm[base + t] = s[t] * inv;
    }
  }
}

// -------- GraphConv gather: h1 (fcat2[:,768:1024]) -> agg (fcat2[:,512:768])
__global__ __launch_bounds__(256)
void gcn_gather2_kernel(const float* __restrict__ edge_norm,
                        ushort* __restrict__ fcat2)
{
  const int tid = threadIdx.x;
  const int n = blockIdx.x * 8 + (tid >> 5);
  const int lane = tid & 31;
  const int b = n / L_, k = n - b * L_;
  const int j0 = max(0, k - 10), j1 = min(L_ - 1, k + 10);
  float acc[8] = {};
  for (int j = j0; j <= j1; ++j) {
    const float w = edge_norm[b * EPB_ + edge_prefix(j) + (k - max(0, j - 10))];
    bf16x8 v = *(const bf16x8*)&fcat2[(size_t)(b * L_ + j) * 1024 + 768 + lane * 8];
#pragma unroll
    for (int i = 0; i < 8; ++i) acc[i] = fmaf(b2f((ushort)v[i]), w, acc[i]);
  }
  bf16x8 o;
#pragma unroll
  for (int i = 0; i < 8; ++i) o[i] = (short)f2b(acc[i]);
  *(bf16x8*)&fcat2[(size_t)n * 1024 + 512 + lane * 8] = o;
}

// ------------- final tiny GEMM: out = hid(bf16) @ clf2_w^T + clf2_b --------
__global__ __launch_bounds__(256)
void clf2_kernel(const ushort* __restrict__ hid, const float* __restrict__ w,
                 const float* __restrict__ bias, float* __restrict__ out)
{
  __shared__ float wsm[7 * H_];
  const int tid = threadIdx.x;
  for (int i = tid; i < 7 * H_; i += 256) wsm[i] = w[i];
  __syncthreads();
  const int idx = blockIdx.x * 256 + threadIdx.x;
  if (idx < N_ * 7) {
    const int n = idx / 7, t = idx - n * 7;
    const ushort* hp = hid + (size_t)n * H_;
    const float* wp = wsm + t * H_;
    float acc = bias[t];
    for (int d0 = 0; d0 < H_; d0 += 8) {
      bf16x8 v = *(const bf16x8*)(hp + d0);
#pragma unroll
      for (int i = 0; i < 8; ++i) acc = fmaf(b2f((ushort)v[i]), wp[d0 + i], acc);
    }
    out[idx] = acc;
  }
}

extern "C" void kernel_launch(void* const* d_in, const int* in_sizes, int n_in,
                              void* d_out, int out_size, void* d_ws, size_t ws_size,
                              hipStream_t stream)
{
  const float* x          = (const float*)d_in[0];
  const float* in_proj_w  = (const float*)d_in[1];
  const float* in_proj_b  = (const float*)d_in[2];
  const float* out_proj_w = (const float*)d_in[3];
  const float* out_proj_b = (const float*)d_in[4];
  const float* ln1_g      = (const float*)d_in[5];
  const float* ln1_b      = (const float*)d_in[6];
  const float* ff1_w      = (const float*)d_in[7];
  const float* ff1_b      = (const float*)d_in[8];
  const float* ff2_w      = (const float*)d_in[9];
  const float* ff2_b      = (const float*)d_in[10];
  const float* ln2_g      = (const float*)d_in[11];
  const float* ln2_b      = (const float*)d_in[12];
  const float* to_w       = (const float*)d_in[13];
  const float* to_b       = (const float*)d_in[14];
  const float* att_w      = (const float*)d_in[15];
  const float* rgcn_basis = (const float*)d_in[16];
  const float* rgcn_comp  = (const float*)d_in[17];
  const float* rgcn_root  = (const float*)d_in[18];
  const float* rgcn_bias  = (const float*)d_in[19];
  const float* gc_rel_w   = (const float*)d_in[20];
  const float* gc_rel_b   = (const float*)d_in[21];
  const float* gc_root_w  = (const float*)d_in[22];
  const float* clf1_w     = (const float*)d_in[23];
  const float* clf1_b     = (const float*)d_in[24];
  const float* clf2_w     = (const float*)d_in[25];
  const float* clf2_b     = (const float*)d_in[26];
  const int*   speaker    = (const int*)d_in[27];
  float* out = (float*)d_out;
  char* p = (char*)d_ws;

  // ---- workspace regions ----
  // R1 (65MB): qkvb bf16 -> ff bf16 -> combo bf16 (N x 2816)
  ushort* R1b    = (ushort*)p;
  p += (size_t)N_ * 2304 * 4;
  // R2 (21.6MB): aprojB/ffoB bf16 ; tail: edge_norm f32
  ushort* aprojB = (ushort*)p;
  ushort* ffoB   = aprojB;
  float*  en     = (float*)(p + (size_t)N_ * 512 * 4);
  p += (size_t)N_ * 768 * 4;
  // R3 (21.6MB): vt bf16 (attn) -> hidB bf16
  ushort* vt    = (ushort*)p;
  ushort* hidB  = (ushort*)p;
  p += (size_t)N_ * 768 * 4;
  // R4 (10.8MB): xb (persists through ln1)
  ushort* xb    = (ushort*)p;
  p += (size_t)N_ * 768 * 2;
  // R5 (10.8MB): hb bf16
  ushort* hb    = (ushort*)p;
  p += (size_t)N_ * 768 * 2;
  // R6 (14.4MB): ctxb (attn out, N x 768) -> fcat2 bf16 (N x 1024)
  ushort* fcat2 = (ushort*)p;
  ushort* ctxb  = (ushort*)p;
  p += (size_t)N_ * 1024 * 2;
  // weights
  ushort* in_projb = (ushort*)p; p += (size_t)2304 * 768 * 2;
  ushort* out_projb= (ushort*)p; p += (size_t)768 * 768 * 2;
  ushort* ff1b     = (ushort*)p; p += (size_t)2048 * 768 * 2;
  ushort* ff2b     = (ushort*)p; p += (size_t)768 * 2048 * 2;
  ushort* tob      = (ushort*)p; p += (size_t)512 * 768 * 2;
  ushort* combw    = (ushort*)p; p += (size_t)NC_ * 512 * 2;
  ushort* clf1b16  = (ushort*)p; p += (size_t)256 * 768 * 2;
  ushort* Wp       = (ushort*)p; p += (size_t)256 * 1024 * 2;   // [W1a|Wc|Wd]
  ushort* grelrootT= (ushort*)p; p += (size_t)512 * 256 * 2;    // [gc_rel^T; gc_root^T]
  float*  bias_comb= (float*)p;  p += NC_ * 4;
  float*  bias2    = (float*)p;  p += 256 * 4;

  // ---- prep (1 dispatch) + Wcd GEMM ----
  PrepArgs pa;
  pa.cin[0] = x;          pa.cout[0] = xb;        pa.n4[0] = N_ * 768 / 4;
  pa.cin[1] = in_proj_w;  pa.cout[1] = in_projb;  pa.n4[1] = 2304 * 768 / 4;
  pa.cin[2] = out_proj_w; pa.cout[2] = out_projb; pa.n4[2] = 768 * 768 / 4;
  pa.cin[3] = ff1_w;      pa.cout[3] = ff1b;      pa.n4[3] = 2048 * 768 / 4;
  pa.cin[4] = ff2_w;      pa.cout[4] = ff2b;      pa.n4[4] = 768 * 2048 / 4;
  pa.cin[5] = to_w;       pa.cout[5] = tob;       pa.n4[5] = 512 * 768 / 4;
  pa.cin[6] = clf1_w;     pa.cout[6] = clf1b16;   pa.n4[6] = 256 * 768 / 4;
  pa.rb = rgcn_bias; pa.grel = gc_rel_w; pa.groot = gc_root_w;
  pa.clf1w = clf1_w; pa.clf1bias = clf1_b; pa.grelb = gc_rel_b;
  pa.attw = att_w; pa.basis = rgcn_basis; pa.comp = rgcn_comp; pa.root = rgcn_root;
  pa.bias_comb = bias_comb; pa.grelrootT = grelrootT; pa.Wp = Wp;
  pa.bias2 = bias2; pa.combw = combw;
  prep_kernel<<<dim3(768, 9), 256, 0, stream>>>(pa);
  // Wp[:,512:1024] = clf1[:,512:768] @ [gc_rel^T; gc_root^T]^T
  mgemm64_kernel<false, false><<<dim3(8, 2), 256, 0, stream>>>(
      clf1b16 + 512, grelrootT, nullptr, Wp + 512, 256, 768, 256, 1024);

  // ---- main pipeline ----
  // qkvb = bf16(x @ in_proj^T + b)
  mgemm_kernel<true, false><<<dim3(18, 55), 256, 0, stream>>>(
      xb, in_projb, in_proj_b, R1b, 768, 768, 768, 2304);
  vtrans_kernel<<<dim3(24, 4, 64), 256, 0, stream>>>(R1b, vt);
  attnM_kernel<<<448, 256, 0, stream>>>(R1b, vt, ctxb);
  // aprojB = bf16(ctx @ out_proj^T + b)    (BN=64: 660 blocks)
  mgemm64_kernel<true, false><<<dim3(12, 55), 256, 0, stream>>>(
      ctxb, out_projb, out_proj_b, aprojB, 768, 768, 768, 768);
  ln_kernel<<<N_, 256, 0, stream>>>(xb, aprojB, ln1_g, ln1_b, hb);
  // ff = relu(h @ ff1^T + b)
  mgemm_kernel<true, true><<<dim3(16, 55), 256, 0, stream>>>(
      hb, ff1b, ff1_b, R1b, 768, 768, 768, 2048);
  // ffoB = bf16(ff @ ff2^T + b)
  mgemm64_kernel<true, false><<<dim3(12, 55), 256, 0, stream>>>(
      R1b, ff2b, ff2_b, ffoB, 2048, 2048, 2048, 768);
  ln_kernel<<<N_, 256, 0, stream>>>(hb, ffoB, ln2_g, ln2_b, hb);
  // feats -> fcat2[:, 0:512]  (ldc = 1024)
  mgemm64_kernel<true, false><<<dim3(8, 55), 256, 0, stream>>>(
      hb, tob, to_b, fcat2, 768, 768, 768, 1024);
  // combo = bf16(feats @ [attw_t|wrel_t|root_t]^T + bias_comb)  (lda = 1024)
  mgemm_kernel<true, false><<<dim3(22, 55), 256, 0, stream>>>(
      fcat2, combw, bias_comb, R1b, 512, 1024, 512, NC_);
  graphfront_kernel<<<N_ / 8 + N_, 256, 0, stream>>>(R1b, fcat2, speaker, en);
  gcn_gather2_kernel<<<N_ / 8, 256, 0, stream>>>(en, fcat2);
  // hid = relu([feats|agg|h1] @ [W1a|Wc|Wd]^T + bias2)   (K = 1024)
  mgemm64_kernel<true, true><<<dim3(4, 55), 256, 0, stream>>>(
      fcat2, Wp, bias2, hidB, 1024, 1024, 1024, 256);
  clf2_kernel<<<(N_ * 7 + 255) / 256, 256, 0, stream>>>(hidB, clf2_w, clf2_b, out);
}

// Round 14
// 301.928 us; speedup vs baseline: 1.1749x; 1.0020x over previous
//
#include <hip/hip_runtime.h>
#include <hip/hip_bf16.h>
#include <math.h>

#define L_   110
#define B_   64
#define N_   7040
#define U_   768
#define G_   512
#define H_   256
#define FF_  2048
#define EPB_ 2200
#define NC_  2816   // combined att_w(512) + wrel(2048) + root(256)

typedef __attribute__((ext_vector_type(4))) float f32x4;
typedef __attribute__((ext_vector_type(8))) short bf16x8;

__device__ __forceinline__ ushort f2b(float f) {
  union { __hip_bfloat16 h; ushort u; } cv;
  cv.h = __float2bfloat16(f);
  return cv.u;
}
__device__ __forceinline__ float b2f(ushort u) {
  union { float f; unsigned int i; } cv; cv.i = ((unsigned int)u) << 16; return cv.f;
}

// prefix(j) = number of edges with src-row j' < j within one dialogue
__device__ __forceinline__ int edge_prefix(int j) {
  if (j <= 10)  return j * 11 + (j * (j - 1)) / 2;
  if (j <= 100) return 155 + (j - 10) * 21;
  return 2045 + ((141 - j) * (j - 100)) / 2;
}

// ================= single prep kernel ======================================
struct PrepArgs {
  const float* cin[7]; ushort* cout[7]; int n4[7];
  const float* rb; const float* grel; const float* groot;
  const float* clf1w; const float* clf1bias; const float* grelb;
  const float* attw; const float* basis; const float* comp; const float* root;
  float* bias_comb; ushort* grelrootT; ushort* Wp; float* bias2; ushort* combw;
};

__global__ __launch_bounds__(256)
void prep_kernel(PrepArgs a)
{
  __shared__ float t[32][33];
  __shared__ float cs[240];
  const int y = blockIdx.y;
  const int tid = threadIdx.x;
  if (y < 7) {
    const int n4 = a.n4[y];
    const float* __restrict__ in = a.cin[y];
    ushort* __restrict__ out = a.cout[y];
    for (int i = blockIdx.x * 256 + tid; i < n4; i += gridDim.x * 256) {
      float4 v = ((const float4*)in)[i];
      ushort4 o;
      o.x = f2b(v.x); o.y = f2b(v.y); o.z = f2b(v.z); o.w = f2b(v.w);
      ((ushort4*)out)[i] = o;
    }
  } else if (y == 7) {
    const int total = NC_ + 65536 + 65536 + 131072 + 256;
    for (int i = blockIdx.x * 256 + tid; i < total; i += gridDim.x * 256) {
      if (i < NC_) {
        a.bias_comb[i] = (i < 2560) ? 0.f : a.rb[i - 2560];
      } else if (i < NC_ + 65536) {
        const int j = i - NC_;
        const int k = j >> 8, c = j & 255;
        a.grelrootT[(size_t)c * 256 + k] = f2b(a.grel[j]);
      } else if (i < NC_ + 131072) {
        const int j = i - NC_ - 65536;
        const int k = j >> 8, c = j & 255;
        a.grelrootT[(size_t)(256 + c) * 256 + k] = f2b(a.groot[j]);
      } else if (i < NC_ + 131072 + 131072) {
        const int j = i - NC_ - 131072;
        const int o = j >> 9, c = j & 511;
        a.Wp[(size_t)o * 1024 + c] = f2b(a.clf1w[(size_t)o * 768 + c]);
      } else {
        const int tt = i - (NC_ + 131072 + 131072);
        float s = a.clf1bias[tt];
        for (int k = 0; k < 256; ++k)
          s = fmaf(a.clf1w[(size_t)tt * 768 + 512 + k], a.grelb[k], s);
        a.bias2[tt] = s;
      }
    }
  } else {
    const int tx = tid & 31, ty = tid >> 5;
    if (blockIdx.x < 256) {
      const int r0 = (blockIdx.x >> 4) * 32, c0 = (blockIdx.x & 15) * 32;
      for (int i = ty; i < 32; i += 8)
        t[i][tx] = a.attw[(size_t)(r0 + i) * 512 + c0 + tx];
      __syncthreads();
      for (int i = ty; i < 32; i += 8)
        a.combw[(size_t)(c0 + i) * 512 + r0 + tx] = f2b(t[tx][i]);
    } else if (blockIdx.x < 384) {
      const int t2 = blockIdx.x - 256;
      const int g0 = (t2 & 15) * 32, h0 = (t2 >> 4) * 32;
      if (tid < 240) cs[tid] = a.comp[tid];
      for (int i = ty; i < 32; i += 8)
        t[i][tx] = a.root[(size_t)(g0 + i) * 256 + h0 + tx];
      __syncthreads();
      for (int i = ty; i < 32; i += 8)
        a.combw[(size_t)(2560 + h0 + i) * 512 + g0 + tx] = f2b(t[tx][i]);
      float acc[8][4] = {};
      for (int bb = 0; bb < 30; ++bb) {
        const float* bp = a.basis + (size_t)bb * (G_ * H_);
#pragma unroll
        for (int k = 0; k < 4; ++k) {
          float v = bp[(size_t)(g0 + ty + 8 * k) * 256 + h0 + tx];
#pragma unroll
          for (int r = 0; r < 8; ++r) acc[r][k] = fmaf(cs[r * 30 + bb], v, acc[r][k]);
        }
      }
      for (int r = 0; r < 8; ++r) {
        __syncthreads();
#pragma unroll
        for (int k = 0; k < 4; ++k) t[ty + 8 * k][tx] = acc[r][k];
        __syncthreads();
        for (int i = ty; i < 32; i += 8)
          a.combw[(size_t)(512 + r * 256 + h0 + i) * 512 + g0 + tx] = f2b(t[tx][i]);
      }
    }
  }
}

// ===================== bf16 MFMA GEMM, 128x128 tile ========================
template<bool BIAS, bool RELU>
__global__ __launch_bounds__(256)
void mgemm_kernel(const ushort* __restrict__ A, const ushort* __restrict__ B,
                  const float* __restrict__ bias, ushort* __restrict__ Cb,
                  int K, int lda, int ldb, int ldc)
{
  __shared__ ushort sA[128 * 64];
  __shared__ ushort sB[128 * 64];
  const int tid = threadIdx.x;
  const int w = tid >> 6, l = tid & 63;

  const int gx = gridDim.x;
  const int nwg = gx * gridDim.y;
  const int lid = blockIdx.y * gx + blockIdx.x;
  const int q = nwg >> 3, r = nwg & 7;
  const int xcd = lid & 7, pos = lid >> 3;
  const int nlid = (xcd < r ? xcd * (q + 1) : r * (q + 1) + (xcd - r) * q) + pos;
  const int m0 = (nlid / gx) * 128, n0 = (nlid % gx) * 128;

  const int srow = l >> 3, sg = l & 7, rbase = w * 32;
  const int wr = w >> 1, wc = w & 1;
  const int lrow = l & 15, lk = l >> 4;
  const int xm = (l & 7) << 4;
  const int kb0 = (lk * 16) ^ xm;
  int aoff[4], boff[4];
#pragma unroll
  for (int i = 0; i < 4; ++i) {
    aoff[i] = (wr * 64 + i * 16 + lrow) * 128 + kb0;
    boff[i] = (wc * 64 + i * 16 + lrow) * 128 + kb0;
  }

  f32x4 acc[4][4];
#pragma unroll
  for (int i = 0; i < 4; ++i)
#pragma unroll
    for (int j = 0; j < 4; ++j) acc[i][j] = (f32x4){0.f, 0.f, 0.f, 0.f};

#define STAGE(k0)                                                              \
  {                                                                            \
    _Pragma("unroll")                                                          \
    for (int i = 0; i < 4; ++i) {                                              \
      const int trow = rbase + i * 8 + srow;                                   \
      const int koff = (sg * 8) ^ ((trow & 7) << 3);                           \
      const ushort* ga = A + (size_t)(m0 + trow) * lda + (k0) + koff;          \
      const ushort* gb = B + (size_t)(n0 + trow) * ldb + (k0) + koff;          \
      __builtin_amdgcn_global_load_lds(                                        \
          (const __attribute__((address_space(1))) void*)ga,                   \
          (__attribute__((address_space(3))) void*)&sA[(rbase + i * 8) * 64],  \
          16, 0, 0);                                                           \
      __builtin_amdgcn_global_load_lds(                                        \
          (const __attribute__((address_space(1))) void*)gb,                   \
          (__attribute__((address_space(3))) void*)&sB[(rbase + i * 8) * 64],  \
          16, 0, 0);                                                           \
    }                                                                          \
  }

  STAGE(0)
  for (int kt = 0;;) {
    __syncthreads();
#pragma unroll
    for (int h = 0; h < 2; ++h) {
      const int hx = h * 64;
      bf16x8 af[4], bfr[4];
#pragma unroll
      for (int i = 0; i < 4; ++i) {
        af[i]  = *(const bf16x8*)&sA[(aoff[i] ^ hx) >> 1];
        bfr[i] = *(const bf16x8*)&sB[(boff[i] ^ hx) >> 1];
      }
#pragma unroll
      for (int mi = 0; mi < 4; ++mi)
#pragma unroll
        for (int ni = 0; ni < 4; ++ni)
          acc[mi][ni] = __builtin_amdgcn_mfma_f32_16x16x32_bf16(
              af[mi], bfr[ni], acc[mi][ni], 0, 0, 0);
    }
    kt += 64;
    if (kt >= K) break;
    __syncthreads();
    STAGE(kt)
  }
#undef STAGE

  const int orow = m0 + wr * 64 + lk * 4;
  const int ocol = n0 + wc * 64 + lrow;
#pragma unroll
  for (int mi = 0; mi < 4; ++mi) {
#pragma unroll
    for (int r2 = 0; r2 < 4; ++r2) {
      const int row = orow + mi * 16 + r2;
#pragma unroll
      for (int ni = 0; ni < 4; ++ni) {
        const int col = ocol + ni * 16;
        float v = acc[mi][ni][r2];
        if constexpr (BIAS) v += bias[col];
        if constexpr (RELU) v = fmaxf(v, 0.f);
        Cb[(size_t)row * ldc + col] = f2b(v);
      }
    }
  }
}

// ===================== bf16 MFMA GEMM, 128x64 tile (narrow N) ==============
template<bool BIAS, bool RELU>
__global__ __launch_bounds__(256)
void mgemm64_kernel(const ushort* __restrict__ A, const ushort* __restrict__ B,
                    const float* __restrict__ bias, ushort* __restrict__ Cb,
                    int K, int lda, int ldb, int ldc)
{
  __shared__ ushort sA[128 * 64];
  __shared__ ushort sB[64 * 64];
  const int tid = threadIdx.x;
  const int w = tid >> 6, l = tid & 63;

  const int gx = gridDim.x;
  const int nwg = gx * gridDim.y;
  const int lid = blockIdx.y * gx + blockIdx.x;
  const int q = nwg >> 3, r = nwg & 7;
  const int xcd = lid & 7, pos = lid >> 3;
  const int nlid = (xcd < r ? xcd * (q + 1) : r * (q + 1) + (xcd - r) * q) + pos;
  const int m0 = (nlid / gx) * 128, n0 = (nlid % gx) * 64;

  const int srow = l >> 3, sg = l & 7;
  const int lrow = l & 15, lk = l >> 4;
  const int xm = (l & 7) << 4;
  const int kb0 = (lk * 16) ^ xm;
  int aoff[2], boff[4];
#pragma unroll
  for (int i = 0; i < 2; ++i) aoff[i] = (w * 32 + i * 16 + lrow) * 128 + kb0;
#pragma unroll
  for (int i = 0; i < 4; ++i) boff[i] = (i * 16 + lrow) * 128 + kb0;

  f32x4 acc[2][4];
#pragma unroll
  for (int i = 0; i < 2; ++i)
#pragma unroll
    for (int j = 0; j < 4; ++j) acc[i][j] = (f32x4){0.f, 0.f, 0.f, 0.f};

#define STAGE64(k0)                                                            \
  {                                                                            \
    _Pragma("unroll")                                                          \
    for (int i = 0; i < 4; ++i) {                                              \
      const int trow = w * 32 + i * 8 + srow;                                  \
      const int koff = (sg * 8) ^ ((trow & 7) << 3);                           \
      const ushort* ga = A + (size_t)(m0 + trow) * lda + (k0) + koff;          \
      __builtin_amdgcn_global_load_lds(                                        \
          (const __attribute__((address_space(1))) void*)ga,                   \
          (__attribute__((address_space(3))) void*)&sA[(w * 32 + i * 8) * 64], \
          16, 0, 0);                                                           \
    }                                                                          \
    _Pragma("unroll")                                                          \
    for (int i = 0; i < 2; ++i) {                                              \
      const int trow = w * 16 + i * 8 + srow;                                  \
      const int koff = (sg * 8) ^ ((trow & 7) << 3);                           \
      const ushort* gb = B + (size_t)(n0 + trow) * ldb + (k0) + koff;          \
      __builtin_amdgcn_global_load_lds(                                        \
          (const __attribute__((address_space(1))) void*)gb,                   \
          (__attribute__((address_space(3))) void*)&sB[(w * 16 + i * 8) * 64], \
          16, 0, 0);                                                           \
    }                                                                          \
  }

  STAGE64(0)
  for (int kt = 0;;) {
    __syncthreads();
#pragma unroll
    for (int h = 0; h < 2; ++h) {
      const int hx = h * 64;
      bf16x8 af[2], bfr[4];
#pragma unroll
      for (int i = 0; i < 2; ++i) af[i] = *(const bf16x8*)&sA[(aoff[i] ^ hx) >> 1];
#pragma unroll
      for (int i = 0; i < 4; ++i) bfr[i] = *(const bf16x8*)&sB[(boff[i] ^ hx) >> 1];
#pragma unroll
      for (int mi = 0; mi < 2; ++mi)
#pragma unroll
        for (int ni = 0; ni < 4; ++ni)
          acc[mi][ni] = __builtin_amdgcn_mfma_f32_16x16x32_bf16(
              af[mi], bfr[ni], acc[mi][ni], 0, 0, 0);
    }
    kt += 64;
    if (kt >= K) break;
    __syncthreads();
    STAGE64(kt)
  }
#undef STAGE64

  const int orow = m0 + w * 32 + lk * 4;
  const int ocol = n0 + lrow;
#pragma unroll
  for (int mi = 0; mi < 2; ++mi) {
#pragma unroll
    for (int r2 = 0; r2 < 4; ++r2) {
      const int row = orow + mi * 16 + r2;
#pragma unroll
      for (int ni = 0; ni < 4; ++ni) {
        const int col = ocol + ni * 16;
        float v = acc[mi][ni][r2];
        if constexpr (BIAS) v += bias[col];
        if constexpr (RELU) v = fmaxf(v, 0.f);
        Cb[(size_t)row * ldc + col] = f2b(v);
      }
    }
  }
}

// -------- V transpose (ushort2-vectorized): V(110x768) -> vt(768x128) ------
__global__ __launch_bounds__(256)
void vtrans_kernel(const ushort* __restrict__ qkvb, ushort* __restrict__ vt)
{
  __shared__ ushort t[32][34];
  const int b = blockIdx.z;
  const int r0 = blockIdx.y * 32;
  const int c0 = blockIdx.x * 32;
  const int tid = threadIdx.x;
  for (int e = tid; e < 512; e += 256) {
    const int ri = e >> 4, ci2 = (e & 15) * 2;
    ushort2 v = make_ushort2(0, 0);
    if (r0 + ri < L_)
      v = *(const ushort2*)&qkvb[((size_t)(b * L_) + r0 + ri) * 2304 + 1536 + c0 + ci2];
    t[ri][ci2] = v.x; t[ri][ci2 + 1] = v.y;
  }
  __syncthreads();
  for (int e = tid; e < 512; e += 256) {
    const int ci = e >> 4, ri2 = (e & 15) * 2;
    ushort2 o = make_ushort2(t[ri2][ci], t[ri2 + 1][ci]);
    *(ushort2*)&vt[((size_t)b * 768 + c0 + ci) * 128 + r0 + ri2] = o;
  }
}

// -------- MFMA attention: 448 blocks, XCD-grouped ------------------------
__global__ __launch_bounds__(256)
void attnM_kernel(const ushort* __restrict__ qkvb, const ushort* __restrict__ vt,
                  ushort* __restrict__ ctxb)
{
  const int wg = blockIdx.x;
  const int xcd = wg & 7, slot = wg >> 3;
  const int b = xcd * 8 + slot / 7;
  const int qr0 = (slot % 7) * 16;
  const int tid = threadIdx.x, w = tid >> 6, l = tid & 63;
  __shared__ float  sS[16 * 128];
  __shared__ ushort sP[16 * 128];
  const int lrow = l & 15, lq = l >> 4;

  const ushort* Qbase = qkvb + ((size_t)(b * L_) + qr0 + lrow) * 2304 + lq * 8;
  f32x4 accS[2] = {{0.f,0.f,0.f,0.f},{0.f,0.f,0.f,0.f}};
  const int nf0 = w * 2;
  for (int k0 = 0; k0 < 768; k0 += 32) {
    bf16x8 aq = *(const bf16x8*)(Qbase + k0);
#pragma unroll
    for (int f = 0; f < 2; ++f) {
      const int nf = nf0 + f;
      if (nf < 7) {
        const ushort* Kp = qkvb + ((size_t)(b * L_) + nf * 16 + lrow) * 2304
                         + 768 + k0 + lq * 8;
        bf16x8 bk = *(const bf16x8*)Kp;
        accS[f] = __builtin_amdgcn_mfma_f32_16x16x32_bf16(aq, bk, accS[f], 0, 0, 0);
      }
    }
  }
  const float scale = 0.03608439182435161f;  // 1/sqrt(768)
#pragma unroll
  for (int f = 0; f < 2; ++f) {
    const int nf = nf0 + f;
    if (nf < 7) {
#pragma unroll
      for (int r = 0; r < 4; ++r)
        sS[(lq * 4 + r) * 128 + nf * 16 + lrow] = accS[f][r] * scale;
    }
  }
  __syncthreads();

  {
    const int row = w * 4 + lq;
    const int c0 = lrow;
    float m = -1e30f;
    for (int c = c0; c < L_; c += 16) m = fmaxf(m, sS[row * 128 + c]);
#pragma unroll
    for (int off = 8; off; off >>= 1) m = fmaxf(m, __shfl_xor(m, off));
    float pv[7];
    float sum = 0.f;
#pragma unroll
    for (int i = 0; i < 7; ++i) {
      const int c = c0 + i * 16;
      float e = (c < L_) ? __expf(sS[row * 128 + c] - m) : 0.f;
      pv[i] = e; sum += e;
    }
#pragma unroll
    for (int off = 8; off; off >>= 1) sum += __shfl_xor(sum, off);
    const float inv = 1.f / sum;
#pragma unroll
    for (int i = 0; i < 8; ++i) {
      const int c = c0 + i * 16;
      ushort pb = (i < 7 && c < L_) ? f2b(pv[i < 7 ? i : 0] * inv) : (ushort)0;
      const int g = (c >> 3) ^ (row & 7);
      sP[row * 128 + g * 8 + (c & 7)] = pb;
    }
  }
  __syncthreads();

  f32x4 accO[12];
#pragma unroll
  for (int i = 0; i < 12; ++i) accO[i] = (f32x4){0.f, 0.f, 0.f, 0.f};
#pragma unroll
  for (int ks = 0; ks < 4; ++ks) {
    const int k = ks * 32 + lq * 8;
    const int g = (k >> 3) ^ (lrow & 7);
    bf16x8 ap = *(const bf16x8*)&sP[lrow * 128 + g * 8];
#pragma unroll
    for (int i = 0; i < 12; ++i) {
      const int col = w * 192 + i * 16 + lrow;
      bf16x8 bv = *(const bf16x8*)(vt + ((size_t)b * 768 + col) * 128 + k);
      accO[i] = __builtin_amdgcn_mfma_f32_16x16x32_bf16(ap, bv, accO[i], 0, 0, 0);
    }
  }
#pragma unroll
  for (int i = 0; i < 12; ++i) {
    const int col = w * 192 + i * 16 + lrow;
#pragma unroll
    for (int r = 0; r < 4; ++r) {
      const int row = qr0 + lq * 4 + r;
      if (row < L_)
        ctxb[((size_t)b * L_ + row) * 768 + col] = f2b(accO[i][r]);
    }
  }
}

// ------- LayerNorm(A[bf16] + Bres[bf16]) -> bf16, vectorized (8 rows/block)
// 32 lanes per row, each lane owns 3x bf16x8 (16B accesses).
__global__ __launch_bounds__(256)
void ln8_kernel(const ushort* __restrict__ Ab, const ushort* __restrict__ Bres,
                const float* __restrict__ g, const float* __restrict__ beta,
                ushort* __restrict__ outb)
{
  const int tid = threadIdx.x;
  const int rr = tid >> 5;              // row within block, 0..7
  const int lane = tid & 31;
  const size_t row = (size_t)blockIdx.x * 8 + rr;
  const ushort* ap = Ab + row * U_;
  const ushort* bp = Bres + row * U_;
  float v[24];
  float s = 0.f, sq = 0.f;
#pragma unroll
  for (int t = 0; t < 3; ++t) {
    bf16x8 av = *(const bf16x8*)(ap + t * 256 + lane * 8);
    bf16x8 bv = *(const bf16x8*)(bp + t * 256 + lane * 8);
#pragma unroll
    for (int i = 0; i < 8; ++i) {
      float xv = b2f((ushort)av[i]) + b2f((ushort)bv[i]);
      v[t * 8 + i] = xv; s += xv; sq += xv * xv;
    }
  }
  // reduce over the aligned 32-lane group (stays within the wave)
#pragma unroll
  for (int off = 16; off; off >>= 1) {
    s += __shfl_xor(s, off);
    sq += __shfl_xor(sq, off);
  }
  const float m = s * (1.f / 768.f);
  const float rstd = rsqrtf(sq * (1.f / 768.f) - m * m + 1e-5f);
  ushort* op = outb + row * U_;
#pragma unroll
  for (int t = 0; t < 3; ++t) {
    bf16x8 o;
#pragma unroll
    for (int i = 0; i < 8; ++i) {
      const int c = t * 256 + lane * 8 + i;
      o[i] = (short)f2b((v[t * 8 + i] - m) * rstd * g[c] + beta[c]);
    }
    *(bf16x8*)(op + t * 256 + lane * 8) = o;
  }
}

// ---- graph front: {RGCN gather -> fcat2[:,768:1024] | edge softmax} -------
__global__ __launch_bounds__(256)
void graphfront_kernel(const ushort* __restrict__ combo, ushort* __restrict__ fcat2,
                       const int* __restrict__ speaker, float* __restrict__ edge_norm)
{
  const int tid = threadIdx.x;
  if (blockIdx.x < N_ / 8) {
    const int n = blockIdx.x * 8 + (tid >> 5);
    const int lane = tid & 31;
    const int b = n / L_, k = n - b * L_;
    const int j0 = max(0, k - 10), j1 = min(L_ - 1, k + 10);
    const int spk = speaker[n];
    float inv[4];
    {
      int cn[4] = {0, 0, 0, 0};
      for (int j = j0; j <= j1; ++j)
        cn[speaker[b * L_ + j] * 2 + (j >= k ? 1 : 0)]++;
#pragma unroll
      for (int q = 0; q < 4; ++q) inv[q] = cn[q] ? 1.f / (float)cn[q] : 0.f;
    }
    float acc[8] = {};
    for (int j = j0; j <= j1; ++j) {
      const int spj = speaker[b * L_ + j];
      const int c = (j >= k) ? 1 : 0;
      const int et = (spj * 2 + spk) * 2 + c;
      const float w = inv[spj * 2 + c];
      bf16x8 v = *(const bf16x8*)&combo[(size_t)(b * L_ + j) * NC_ + 512 + et * 256 + lane * 8];
#pragma unroll
      for (int i = 0; i < 8; ++i) acc[i] = fmaf(b2f((ushort)v[i]), w, acc[i]);
    }
    bf16x8 rt = *(const bf16x8*)&combo[(size_t)n * NC_ + 2560 + lane * 8];
    bf16x8 o;
#pragma unroll
    for (int i = 0; i < 8; ++i) o[i] = (short)f2b(acc[i] + b2f((ushort)rt[i]));
    *(bf16x8*)&fcat2[(size_t)n * 1024 + 768 + lane * 8] = o;
  } else {
    const int bj = blockIdx.x - N_ / 8;
    const int b = bj / L_, j = bj - b * L_;
    const int k0 = max(0, j - 10), k1 = min(L_ - 1, j + 10);
    __shared__ float s[32];
    const int wave = tid >> 6, lane = tid & 63;
    float tr[8];
    {
      bf16x8 tv = *(const bf16x8*)&combo[(size_t)bj * NC_ + lane * 8];
#pragma unroll
      for (int i = 0; i < 8; ++i) tr[i] = b2f((ushort)tv[i]);
    }
    for (int k = k0 + wave; k <= k1; k += 4) {
      bf16x8 v = *(const bf16x8*)&fcat2[(size_t)(b * L_ + k) * 1024 + lane * 8];
      float sc = 0.f;
#pragma unroll
      for (int i = 0; i < 8; ++i) sc = fmaf(b2f((ushort)v[i]), tr[i], sc);
#pragma unroll
      for (int off = 32; off; off >>= 1) sc += __shfl_xor(sc, off);
      if (lane == 0) s[k - k0] = sc;
    }
    __syncthreads();
    if (tid == 0) {
      const int W = k1 - k0 + 1;
      float m = -1e30f;
      for (int t = 0; t < W; ++t) m = fmaxf(m, s[t]);
      float sum = 0.f;
      for (int t = 0; t < W; ++t) { float e = __expf(s[t] - m); s[t] = e; sum += e; }
      const float inv = 1.f / sum;
      const int base = b * EPB_ + edge_prefix(j);
      for (int t = 0; t < W; ++t) edge_norm[base + t] = s[t] * inv;
    }
  }
}

// -------- GraphConv gather: h1 (fcat2[:,768:1024]) -> agg (fcat2[:,512:768])
__global__ __launch_bounds__(256)
void gcn_gather2_kernel(const float* __restrict__ edge_norm,
                        ushort* __restrict__ fcat2)
{
  const int tid = threadIdx.x;
  const int n = blockIdx.x * 8 + (tid >> 5);
  const int lane = tid & 31;
  const int b = n / L_, k = n - b * L_;
  const int j0 = max(0, k - 10), j1 = min(L_ - 1, k + 10);
  float acc[8] = {};
  for (int j = j0; j <= j1; ++j) {
    const float w = edge_norm[b * EPB_ + edge_prefix(j) + (k - max(0, j - 10))];
    bf16x8 v = *(const bf16x8*)&fcat2[(size_t)(b * L_ + j) * 1024 + 768 + lane * 8];
#pragma unroll
    for (int i = 0; i < 8; ++i) acc[i] = fmaf(b2f((ushort)v[i]), w, acc[i]);
  }
  bf16x8 o;
#pragma unroll
  for (int i = 0; i < 8; ++i) o[i] = (short)f2b(acc[i]);
  *(bf16x8*)&fcat2[(size_t)n * 1024 + 512 + lane * 8] = o;
}

// ------------- final tiny GEMM: out = hid(bf16) @ clf2_w^T + clf2_b --------
__global__ __launch_bounds__(256)
void clf2_kernel(const ushort* __restrict__ hid, const float* __restrict__ w,
                 const float* __restrict__ bias, float* __restrict__ out)
{
  __shared__ float wsm[7 * H_];
  const int tid = threadIdx.x;
  for (int i = tid; i < 7 * H_; i += 256) wsm[i] = w[i];
  __syncthreads();
  const int idx = blockIdx.x * 256 + threadIdx.x;
  if (idx < N_ * 7) {
    const int n = idx / 7, t = idx - n * 7;
    const ushort* hp = hid + (size_t)n * H_;
    const float* wp = wsm + t * H_;
    float acc = bias[t];
    for (int d0 = 0; d0 < H_; d0 += 8) {
      bf16x8 v = *(const bf16x8*)(hp + d0);
#pragma unroll
      for (int i = 0; i < 8; ++i) acc = fmaf(b2f((ushort)v[i]), wp[d0 + i], acc);
    }
    out[idx] = acc;
  }
}

extern "C" void kernel_launch(void* const* d_in, const int* in_sizes, int n_in,
                              void* d_out, int out_size, void* d_ws, size_t ws_size,
                              hipStream_t stream)
{
  const float* x          = (const float*)d_in[0];
  const float* in_proj_w  = (const float*)d_in[1];
  const float* in_proj_b  = (const float*)d_in[2];
  const float* out_proj_w = (const float*)d_in[3];
  const float* out_proj_b = (const float*)d_in[4];
  const float* ln1_g      = (const float*)d_in[5];
  const float* ln1_b      = (const float*)d_in[6];
  const float* ff1_w      = (const float*)d_in[7];
  const float* ff1_b      = (const float*)d_in[8];
  const float* ff2_w      = (const float*)d_in[9];
  const float* ff2_b      = (const float*)d_in[10];
  const float* ln2_g      = (const float*)d_in[11];
  const float* ln2_b      = (const float*)d_in[12];
  const float* to_w       = (const float*)d_in[13];
  const float* to_b       = (const float*)d_in[14];
  const float* att_w      = (const float*)d_in[15];
  const float* rgcn_basis = (const float*)d_in[16];
  const float* rgcn_comp  = (const float*)d_in[17];
  const float* rgcn_root  = (const float*)d_in[18];
  const float* rgcn_bias  = (const float*)d_in[19];
  const float* gc_rel_w   = (const float*)d_in[20];
  const float* gc_rel_b   = (const float*)d_in[21];
  const float* gc_root_w  = (const float*)d_in[22];
  const float* clf1_w     = (const float*)d_in[23];
  const float* clf1_b     = (const float*)d_in[24];
  const float* clf2_w     = (const float*)d_in[25];
  const float* clf2_b     = (const float*)d_in[26];
  const int*   speaker    = (const int*)d_in[27];
  float* out = (float*)d_out;
  char* p = (char*)d_ws;

  // ---- workspace regions ----
  // R1 (65MB): qkvb bf16 -> ff bf16 -> combo bf16 (N x 2816)
  ushort* R1b    = (ushort*)p;
  p += (size_t)N_ * 2304 * 4;
  // R2 (21.6MB): aprojB/ffoB bf16 ; tail: edge_norm f32
  ushort* aprojB = (ushort*)p;
  ushort* ffoB   = aprojB;
  float*  en     = (float*)(p + (size_t)N_ * 512 * 4);
  p += (size_t)N_ * 768 * 4;
  // R3 (21.6MB): vt bf16 (attn) -> hidB bf16
  ushort* vt    = (ushort*)p;
  ushort* hidB  = (ushort*)p;
  p += (size_t)N_ * 768 * 4;
  // R4 (10.8MB): xb (persists through ln1)
  ushort* xb    = (ushort*)p;
  p += (size_t)N_ * 768 * 2;
  // R5 (10.8MB): hb bf16
  ushort* hb    = (ushort*)p;
  p += (size_t)N_ * 768 * 2;
  // R6 (14.4MB): ctxb (attn out, N x 768) -> fcat2 bf16 (N x 1024)
  ushort* fcat2 = (ushort*)p;
  ushort* ctxb  = (ushort*)p;
  p += (size_t)N_ * 1024 * 2;
  // weights
  ushort* in_projb = (ushort*)p; p += (size_t)2304 * 768 * 2;
  ushort* out_projb= (ushort*)p; p += (size_t)768 * 768 * 2;
  ushort* ff1b     = (ushort*)p; p += (size_t)2048 * 768 * 2;
  ushort* ff2b     = (ushort*)p; p += (size_t)768 * 2048 * 2;
  ushort* tob      = (ushort*)p; p += (size_t)512 * 768 * 2;
  ushort* combw    = (ushort*)p; p += (size_t)NC_ * 512 * 2;
  ushort* clf1b16  = (ushort*)p; p += (size_t)256 * 768 * 2;
  ushort* Wp       = (ushort*)p; p += (size_t)256 * 1024 * 2;   // [W1a|Wc|Wd]
  ushort* grelrootT= (ushort*)p; p += (size_t)512 * 256 * 2;    // [gc_rel^T; gc_root^T]
  float*  bias_comb= (float*)p;  p += NC_ * 4;
  float*  bias2    = (float*)p;  p += 256 * 4;

  // ---- prep (1 dispatch) + Wcd GEMM ----
  PrepArgs pa;
  pa.cin[0] = x;          pa.cout[0] = xb;        pa.n4[0] = N_ * 768 / 4;
  pa.cin[1] = in_proj_w;  pa.cout[1] = in_projb;  pa.n4[1] = 2304 * 768 / 4;
  pa.cin[2] = out_proj_w; pa.cout[2] = out_projb; pa.n4[2] = 768 * 768 / 4;
  pa.cin[3] = ff1_w;      pa.cout[3] = ff1b;      pa.n4[3] = 2048 * 768 / 4;
  pa.cin[4] = ff2_w;      pa.cout[4] = ff2b;      pa.n4[4] = 768 * 2048 / 4;
  pa.cin[5] = to_w;       pa.cout[5] = tob;       pa.n4[5] = 512 * 768 / 4;
  pa.cin[6] = clf1_w;     pa.cout[6] = clf1b16;   pa.n4[6] = 256 * 768 / 4;
  pa.rb = rgcn_bias; pa.grel = gc_rel_w; pa.groot = gc_root_w;
  pa.clf1w = clf1_w; pa.clf1bias = clf1_b; pa.grelb = gc_rel_b;
  pa.attw = att_w; pa.basis = rgcn_basis; pa.comp = rgcn_comp; pa.root = rgcn_root;
  pa.bias_comb = bias_comb; pa.grelrootT = grelrootT; pa.Wp = Wp;
  pa.bias2 = bias2; pa.combw = combw;
  prep_kernel<<<dim3(768, 9), 256, 0, stream>>>(pa);
  // Wp[:,512:1024] = clf1[:,512:768] @ [gc_rel^T; gc_root^T]^T
  mgemm64_kernel<false, false><<<dim3(8, 2), 256, 0, stream>>>(
      clf1b16 + 512, grelrootT, nullptr, Wp + 512, 256, 768, 256, 1024);

  // ---- main pipeline ----
  // qkvb = bf16(x @ in_proj^T + b)
  mgemm_kernel<true, false><<<dim3(18, 55), 256, 0, stream>>>(
      xb, in_projb, in_proj_b, R1b, 768, 768, 768, 2304);
  vtrans_kernel<<<dim3(24, 4, 64), 256, 0, stream>>>(R1b, vt);
  attnM_kernel<<<448, 256, 0, stream>>>(R1b, vt, ctxb);
  // aprojB = bf16(ctx @ out_proj^T + b)    (BN=64: 660 blocks)
  mgemm64_kernel<true, false><<<dim3(12, 55), 256, 0, stream>>>(
      ctxb, out_projb, out_proj_b, aprojB, 768, 768, 768, 768);
  ln8_kernel<<<N_ / 8, 256, 0, stream>>>(xb, aprojB, ln1_g, ln1_b, hb);
  // ff = relu(h @ ff1^T + b)
  mgemm_kernel<true, true><<<dim3(16, 55), 256, 0, stream>>>(
      hb, ff1b, ff1_b, R1b, 768, 768, 768, 2048);
  // ffoB = bf16(ff @ ff2^T + b)
  mgemm64_kernel<true, false><<<dim3(12, 55), 256, 0, stream>>>(
      R1b, ff2b, ff2_b, ffoB, 2048, 2048, 2048, 768);
  ln8_kernel<<<N_ / 8, 256, 0, stream>>>(hb, ffoB, ln2_g, ln2_b, hb);
  // feats -> fcat2[:, 0:512]  (ldc = 1024)
  mgemm64_kernel<true, false><<<dim3(8, 55), 256, 0, stream>>>(
      hb, tob, to_b, fcat2, 768, 768, 768, 1024);
  // combo = bf16(feats @ [attw_t|wrel_t|root_t]^T + bias_comb)  (lda = 1024)
  mgemm_kernel<true, false><<<dim3(22, 55), 256, 0, stream>>>(
      fcat2, combw, bias_comb, R1b, 512, 1024, 512, NC_);
  graphfront_kernel<<<N_ / 8 + N_, 256, 0, stream>>>(R1b, fcat2, speaker, en);
  gcn_gather2_kernel<<<N_ / 8, 256, 0, stream>>>(en, fcat2);
  // hid = relu([feats|agg|h1] @ [W1a|Wc|Wd]^T + bias2)   (K = 1024)
  mgemm64_kernel<true, true><<<dim3(4, 55), 256, 0, stream>>>(
      fcat2, Wp, bias2, hidB, 1024, 1024, 1024, 256);
  clf2_kernel<<<(N_ * 7 + 255) / 256, 256, 0, stream>>>(hidB, clf2_w, clf2_b, out);
}

// Round 15
// 300.770 us; speedup vs baseline: 1.1795x; 1.0039x over previous
//
#include <hip/hip_runtime.h>
#include <hip/hip_bf16.h>
#include <math.h>

#define L_   110
#define B_   64
#define N_   7040
#define U_   768
#define G_   512
#define H_   256
#define FF_  2048
#define EPB_ 2200
#define NC_  2816   // combined att_w(512) + wrel(2048) + root(256)

typedef __attribute__((ext_vector_type(4))) float f32x4;
typedef __attribute__((ext_vector_type(8))) short bf16x8;

__device__ __forceinline__ ushort f2b(float f) {
  union { __hip_bfloat16 h; ushort u; } cv;
  cv.h = __float2bfloat16(f);
  return cv.u;
}
__device__ __forceinline__ float b2f(ushort u) {
  union { float f; unsigned int i; } cv; cv.i = ((unsigned int)u) << 16; return cv.f;
}

// prefix(j) = number of edges with src-row j' < j within one dialogue
__device__ __forceinline__ int edge_prefix(int j) {
  if (j <= 10)  return j * 11 + (j * (j - 1)) / 2;
  if (j <= 100) return 155 + (j - 10) * 21;
  return 2045 + ((141 - j) * (j - 100)) / 2;
}

// ================= single prep kernel ======================================
struct PrepArgs {
  const float* cin[7]; ushort* cout[7]; int n4[7];
  const float* rb; const float* grel; const float* groot;
  const float* clf1w; const float* clf1bias; const float* grelb;
  const float* attw; const float* basis; const float* comp; const float* root;
  float* bias_comb; ushort* grelrootT; ushort* Wp; float* bias2; ushort* combw;
};

__global__ __launch_bounds__(256)
void prep_kernel(PrepArgs a)
{
  __shared__ float t[32][33];
  __shared__ float cs[240];
  const int y = blockIdx.y;
  const int tid = threadIdx.x;
  if (y < 7) {
    const int n4 = a.n4[y];
    const float* __restrict__ in = a.cin[y];
    ushort* __restrict__ out = a.cout[y];
    for (int i = blockIdx.x * 256 + tid; i < n4; i += gridDim.x * 256) {
      float4 v = ((const float4*)in)[i];
      ushort4 o;
      o.x = f2b(v.x); o.y = f2b(v.y); o.z = f2b(v.z); o.w = f2b(v.w);
      ((ushort4*)out)[i] = o;
    }
  } else if (y == 7) {
    const int total = NC_ + 65536 + 65536 + 131072 + 256;
    for (int i = blockIdx.x * 256 + tid; i < total; i += gridDim.x * 256) {
      if (i < NC_) {
        a.bias_comb[i] = (i < 2560) ? 0.f : a.rb[i - 2560];
      } else if (i < NC_ + 65536) {
        const int j = i - NC_;
        const int k = j >> 8, c = j & 255;
        a.grelrootT[(size_t)c * 256 + k] = f2b(a.grel[j]);
      } else if (i < NC_ + 131072) {
        const int j = i - NC_ - 65536;
        const int k = j >> 8, c = j & 255;
        a.grelrootT[(size_t)(256 + c) * 256 + k] = f2b(a.groot[j]);
      } else if (i < NC_ + 131072 + 131072) {
        const int j = i - NC_ - 131072;
        const int o = j >> 9, c = j & 511;
        a.Wp[(size_t)o * 1024 + c] = f2b(a.clf1w[(size_t)o * 768 + c]);
      } else {
        const int tt = i - (NC_ + 131072 + 131072);
        float s = a.clf1bias[tt];
        for (int k = 0; k < 256; ++k)
          s = fmaf(a.clf1w[(size_t)tt * 768 + 512 + k], a.grelb[k], s);
        a.bias2[tt] = s;
      }
    }
  } else {
    const int tx = tid & 31, ty = tid >> 5;
    if (blockIdx.x < 256) {
      const int r0 = (blockIdx.x >> 4) * 32, c0 = (blockIdx.x & 15) * 32;
      for (int i = ty; i < 32; i += 8)
        t[i][tx] = a.attw[(size_t)(r0 + i) * 512 + c0 + tx];
      __syncthreads();
      for (int i = ty; i < 32; i += 8)
        a.combw[(size_t)(c0 + i) * 512 + r0 + tx] = f2b(t[tx][i]);
    } else if (blockIdx.x < 384) {
      const int t2 = blockIdx.x - 256;
      const int g0 = (t2 & 15) * 32, h0 = (t2 >> 4) * 32;
      if (tid < 240) cs[tid] = a.comp[tid];
      for (int i = ty; i < 32; i += 8)
        t[i][tx] = a.root[(size_t)(g0 + i) * 256 + h0 + tx];
      __syncthreads();
      for (int i = ty; i < 32; i += 8)
        a.combw[(size_t)(2560 + h0 + i) * 512 + g0 + tx] = f2b(t[tx][i]);
      float acc[8][4] = {};
      for (int bb = 0; bb < 30; ++bb) {
        const float* bp = a.basis + (size_t)bb * (G_ * H_);
#pragma unroll
        for (int k = 0; k < 4; ++k) {
          float v = bp[(size_t)(g0 + ty + 8 * k) * 256 + h0 + tx];
#pragma unroll
          for (int r = 0; r < 8; ++r) acc[r][k] = fmaf(cs[r * 30 + bb], v, acc[r][k]);
        }
      }
      for (int r = 0; r < 8; ++r) {
        __syncthreads();
#pragma unroll
        for (int k = 0; k < 4; ++k) t[ty + 8 * k][tx] = acc[r][k];
        __syncthreads();
        for (int i = ty; i < 32; i += 8)
          a.combw[(size_t)(512 + r * 256 + h0 + i) * 512 + g0 + tx] = f2b(t[tx][i]);
      }
    }
  }
}

// ============ bf16 MFMA GEMM, 64x128 tile (wide-N, high occupancy) =========
// 24KB LDS -> 6 blocks/CU. Same K-order as the 128x128 variant (bit-identical
// per-element accumulation). Grid: (N/128, M/64), XCD-bijective remap.
template<bool BIAS, bool RELU>
__global__ __launch_bounds__(256)
void mgemmW_kernel(const ushort* __restrict__ A, const ushort* __restrict__ B,
                   const float* __restrict__ bias, ushort* __restrict__ Cb,
                   int K, int lda, int ldb, int ldc)
{
  __shared__ ushort sA[64 * 64];
  __shared__ ushort sB[128 * 64];
  const int tid = threadIdx.x;
  const int w = tid >> 6, l = tid & 63;

  const int gx = gridDim.x;
  const int nwg = gx * gridDim.y;
  const int lid = blockIdx.y * gx + blockIdx.x;
  const int q = nwg >> 3, r = nwg & 7;
  const int xcd = lid & 7, pos = lid >> 3;
  const int nlid = (xcd < r ? xcd * (q + 1) : r * (q + 1) + (xcd - r) * q) + pos;
  const int m0 = (nlid / gx) * 64, n0 = (nlid % gx) * 128;

  const int srow = l >> 3, sg = l & 7;
  const int wr = w & 1, wc = w >> 1;       // wave -> (row half of 64, col half of 128)
  const int lrow = l & 15, lk = l >> 4;
  const int xm = (l & 7) << 4;
  const int kb0 = (lk * 16) ^ xm;
  int aoff[2], boff[4];
#pragma unroll
  for (int i = 0; i < 2; ++i) aoff[i] = (wr * 32 + i * 16 + lrow) * 128 + kb0;
#pragma unroll
  for (int i = 0; i < 4; ++i) boff[i] = (wc * 64 + i * 16 + lrow) * 128 + kb0;

  f32x4 acc[2][4];
#pragma unroll
  for (int i = 0; i < 2; ++i)
#pragma unroll
    for (int j = 0; j < 4; ++j) acc[i][j] = (f32x4){0.f, 0.f, 0.f, 0.f};

#define STAGEW(k0)                                                             \
  {                                                                            \
    _Pragma("unroll")                                                          \
    for (int i = 0; i < 2; ++i) {                                              \
      const int trow = w * 16 + i * 8 + srow;                                  \
      const int koff = (sg * 8) ^ ((trow & 7) << 3);                           \
      const ushort* ga = A + (size_t)(m0 + trow) * lda + (k0) + koff;          \
      __builtin_amdgcn_global_load_lds(                                        \
          (const __attribute__((address_space(1))) void*)ga,                   \
          (__attribute__((address_space(3))) void*)&sA[(w * 16 + i * 8) * 64], \
          16, 0, 0);                                                           \
    }                                                                          \
    _Pragma("unroll")                                                          \
    for (int i = 0; i < 4; ++i) {                                              \
      const int trow = w * 32 + i * 8 + srow;                                  \
      const int koff = (sg * 8) ^ ((trow & 7) << 3);                           \
      const ushort* gb = B + (size_t)(n0 + trow) * ldb + (k0) + koff;          \
      __builtin_amdgcn_global_load_lds(                                        \
          (const __attribute__((address_space(1))) void*)gb,                   \
          (__attribute__((address_space(3))) void*)&sB[(w * 32 + i * 8) * 64], \
          16, 0, 0);                                                           \
    }                                                                          \
  }

  STAGEW(0)
  for (int kt = 0;;) {
    __syncthreads();
#pragma unroll
    for (int h = 0; h < 2; ++h) {
      const int hx = h * 64;
      bf16x8 af[2], bfr[4];
#pragma unroll
      for (int i = 0; i < 2; ++i) af[i] = *(const bf16x8*)&sA[(aoff[i] ^ hx) >> 1];
#pragma unroll
      for (int i = 0; i < 4; ++i) bfr[i] = *(const bf16x8*)&sB[(boff[i] ^ hx) >> 1];
#pragma unroll
      for (int mi = 0; mi < 2; ++mi)
#pragma unroll
        for (int ni = 0; ni < 4; ++ni)
          acc[mi][ni] = __builtin_amdgcn_mfma_f32_16x16x32_bf16(
              af[mi], bfr[ni], acc[mi][ni], 0, 0, 0);
    }
    kt += 64;
    if (kt >= K) break;
    __syncthreads();
    STAGEW(kt)
  }
#undef STAGEW

  const int orow = m0 + wr * 32 + lk * 4;
  const int ocol = n0 + wc * 64 + lrow;
#pragma unroll
  for (int mi = 0; mi < 2; ++mi) {
#pragma unroll
    for (int r2 = 0; r2 < 4; ++r2) {
      const int row = orow + mi * 16 + r2;
#pragma unroll
      for (int ni = 0; ni < 4; ++ni) {
        const int col = ocol + ni * 16;
        float v = acc[mi][ni][r2];
        if constexpr (BIAS) v += bias[col];
        if constexpr (RELU) v = fmaxf(v, 0.f);
        Cb[(size_t)row * ldc + col] = f2b(v);
      }
    }
  }
}

// ===================== bf16 MFMA GEMM, 128x64 tile (narrow N) ==============
template<bool BIAS, bool RELU>
__global__ __launch_bounds__(256)
void mgemm64_kernel(const ushort* __restrict__ A, const ushort* __restrict__ B,
                    const float* __restrict__ bias, ushort* __restrict__ Cb,
                    int K, int lda, int ldb, int ldc)
{
  __shared__ ushort sA[128 * 64];
  __shared__ ushort sB[64 * 64];
  const int tid = threadIdx.x;
  const int w = tid >> 6, l = tid & 63;

  const int gx = gridDim.x;
  const int nwg = gx * gridDim.y;
  const int lid = blockIdx.y * gx + blockIdx.x;
  const int q = nwg >> 3, r = nwg & 7;
  const int xcd = lid & 7, pos = lid >> 3;
  const int nlid = (xcd < r ? xcd * (q + 1) : r * (q + 1) + (xcd - r) * q) + pos;
  const int m0 = (nlid / gx) * 128, n0 = (nlid % gx) * 64;

  const int srow = l >> 3, sg = l & 7;
  const int lrow = l & 15, lk = l >> 4;
  const int xm = (l & 7) << 4;
  const int kb0 = (lk * 16) ^ xm;
  int aoff[2], boff[4];
#pragma unroll
  for (int i = 0; i < 2; ++i) aoff[i] = (w * 32 + i * 16 + lrow) * 128 + kb0;
#pragma unroll
  for (int i = 0; i < 4; ++i) boff[i] = (i * 16 + lrow) * 128 + kb0;

  f32x4 acc[2][4];
#pragma unroll
  for (int i = 0; i < 2; ++i)
#pragma unroll
    for (int j = 0; j < 4; ++j) acc[i][j] = (f32x4){0.f, 0.f, 0.f, 0.f};

#define STAGE64(k0)                                                            \
  {                                                                            \
    _Pragma("unroll")                                                          \
    for (int i = 0; i < 4; ++i) {                                              \
      const int trow = w * 32 + i * 8 + srow;                                  \
      const int koff = (sg * 8) ^ ((trow & 7) << 3);                           \
      const ushort* ga = A + (size_t)(m0 + trow) * lda + (k0) + koff;          \
      __builtin_amdgcn_global_load_lds(                                        \
          (const __attribute__((address_space(1))) void*)ga,                   \
          (__attribute__((address_space(3))) void*)&sA[(w * 32 + i * 8) * 64], \
          16, 0, 0);                                                           \
    }                                                                          \
    _Pragma("unroll")                                                          \
    for (int i = 0; i < 2; ++i) {                                              \
      const int trow = w * 16 + i * 8 + srow;                                  \
      const int koff = (sg * 8) ^ ((trow & 7) << 3);                           \
      const ushort* gb = B + (size_t)(n0 + trow) * ldb + (k0) + koff;          \
      __builtin_amdgcn_global_load_lds(                                        \
          (const __attribute__((address_space(1))) void*)gb,                   \
          (__attribute__((address_space(3))) void*)&sB[(w * 16 + i * 8) * 64], \
          16, 0, 0);                                                           \
    }                                                                          \
  }

  STAGE64(0)
  for (int kt = 0;;) {
    __syncthreads();
#pragma unroll
    for (int h = 0; h < 2; ++h) {
      const int hx = h * 64;
      bf16x8 af[2], bfr[4];
#pragma unroll
      for (int i = 0; i < 2; ++i) af[i] = *(const bf16x8*)&sA[(aoff[i] ^ hx) >> 1];
#pragma unroll
      for (int i = 0; i < 4; ++i) bfr[i] = *(const bf16x8*)&sB[(boff[i] ^ hx) >> 1];
#pragma unroll
      for (int mi = 0; mi < 2; ++mi)
#pragma unroll
        for (int ni = 0; ni < 4; ++ni)
          acc[mi][ni] = __builtin_amdgcn_mfma_f32_16x16x32_bf16(
              af[mi], bfr[ni], acc[mi][ni], 0, 0, 0);
    }
    kt += 64;
    if (kt >= K) break;
    __syncthreads();
    STAGE64(kt)
  }
#undef STAGE64

  const int orow = m0 + w * 32 + lk * 4;
  const int ocol = n0 + lrow;
#pragma unroll
  for (int mi = 0; mi < 2; ++mi) {
#pragma unroll
    for (int r2 = 0; r2 < 4; ++r2) {
      const int row = orow + mi * 16 + r2;
#pragma unroll
      for (int ni = 0; ni < 4; ++ni) {
        const int col = ocol + ni * 16;
        float v = acc[mi][ni][r2];
        if constexpr (BIAS) v += bias[col];
        if constexpr (RELU) v = fmaxf(v, 0.f);
        Cb[(size_t)row * ldc + col] = f2b(v);
      }
    }
  }
}

// -------- V transpose (ushort2-vectorized): V(110x768) -> vt(768x128) ------
__global__ __launch_bounds__(256)
void vtrans_kernel(const ushort* __restrict__ qkvb, ushort* __restrict__ vt)
{
  __shared__ ushort t[32][34];
  const int b = blockIdx.z;
  const int r0 = blockIdx.y * 32;
  const int c0 = blockIdx.x * 32;
  const int tid = threadIdx.x;
  for (int e = tid; e < 512; e += 256) {
    const int ri = e >> 4, ci2 = (e & 15) * 2;
    ushort2 v = make_ushort2(0, 0);
    if (r0 + ri < L_)
      v = *(const ushort2*)&qkvb[((size_t)(b * L_) + r0 + ri) * 2304 + 1536 + c0 + ci2];
    t[ri][ci2] = v.x; t[ri][ci2 + 1] = v.y;
  }
  __syncthreads();
  for (int e = tid; e < 512; e += 256) {
    const int ci = e >> 4, ri2 = (e & 15) * 2;
    ushort2 o = make_ushort2(t[ri2][ci], t[ri2 + 1][ci]);
    *(ushort2*)&vt[((size_t)b * 768 + c0 + ci) * 128 + r0 + ri2] = o;
  }
}

// -------- MFMA attention: 448 blocks, XCD-grouped ------------------------
__global__ __launch_bounds__(256)
void attnM_kernel(const ushort* __restrict__ qkvb, const ushort* __restrict__ vt,
                  ushort* __restrict__ ctxb)
{
  const int wg = blockIdx.x;
  const int xcd = wg & 7, slot = wg >> 3;
  const int b = xcd * 8 + slot / 7;
  const int qr0 = (slot % 7) * 16;
  const int tid = threadIdx.x, w = tid >> 6, l = tid & 63;
  __shared__ float  sS[16 * 128];
  __shared__ ushort sP[16 * 128];
  const int lrow = l & 15, lq = l >> 4;

  const ushort* Qbase = qkvb + ((size_t)(b * L_) + qr0 + lrow) * 2304 + lq * 8;
  f32x4 accS[2] = {{0.f,0.f,0.f,0.f},{0.f,0.f,0.f,0.f}};
  const int nf0 = w * 2;
  for (int k0 = 0; k0 < 768; k0 += 32) {
    bf16x8 aq = *(const bf16x8*)(Qbase + k0);
#pragma unroll
    for (int f = 0; f < 2; ++f) {
      const int nf = nf0 + f;
      if (nf < 7) {
        const ushort* Kp = qkvb + ((size_t)(b * L_) + nf * 16 + lrow) * 2304
                         + 768 + k0 + lq * 8;
        bf16x8 bk = *(const bf16x8*)Kp;
        accS[f] = __builtin_amdgcn_mfma_f32_16x16x32_bf16(aq, bk, accS[f], 0, 0, 0);
      }
    }
  }
  const float scale = 0.03608439182435161f;  // 1/sqrt(768)
#pragma unroll
  for (int f = 0; f < 2; ++f) {
    const int nf = nf0 + f;
    if (nf < 7) {
#pragma unroll
      for (int r = 0; r < 4; ++r)
        sS[(lq * 4 + r) * 128 + nf * 16 + lrow] = accS[f][r] * scale;
    }
  }
  __syncthreads();

  {
    const int row = w * 4 + lq;
    const int c0 = lrow;
    float m = -1e30f;
    for (int c = c0; c < L_; c += 16) m = fmaxf(m, sS[row * 128 + c]);
#pragma unroll
    for (int off = 8; off; off >>= 1) m = fmaxf(m, __shfl_xor(m, off));
    float pv[7];
    float sum = 0.f;
#pragma unroll
    for (int i = 0; i < 7; ++i) {
      const int c = c0 + i * 16;
      float e = (c < L_) ? __expf(sS[row * 128 + c] - m) : 0.f;
      pv[i] = e; sum += e;
    }
#pragma unroll
    for (int off = 8; off; off >>= 1) sum += __shfl_xor(sum, off);
    const float inv = 1.f / sum;
#pragma unroll
    for (int i = 0; i < 8; ++i) {
      const int c = c0 + i * 16;
      ushort pb = (i < 7 && c < L_) ? f2b(pv[i < 7 ? i : 0] * inv) : (ushort)0;
      const int g = (c >> 3) ^ (row & 7);
      sP[row * 128 + g * 8 + (c & 7)] = pb;
    }
  }
  __syncthreads();

  f32x4 accO[12];
#pragma unroll
  for (int i = 0; i < 12; ++i) accO[i] = (f32x4){0.f, 0.f, 0.f, 0.f};
#pragma unroll
  for (int ks = 0; ks < 4; ++ks) {
    const int k = ks * 32 + lq * 8;
    const int g = (k >> 3) ^ (lrow & 7);
    bf16x8 ap = *(const bf16x8*)&sP[lrow * 128 + g * 8];
#pragma unroll
    for (int i = 0; i < 12; ++i) {
      const int col = w * 192 + i * 16 + lrow;
      bf16x8 bv = *(const bf16x8*)(vt + ((size_t)b * 768 + col) * 128 + k);
      accO[i] = __builtin_amdgcn_mfma_f32_16x16x32_bf16(ap, bv, accO[i], 0, 0, 0);
    }
  }
#pragma unroll
  for (int i = 0; i < 12; ++i) {
    const int col = w * 192 + i * 16 + lrow;
#pragma unroll
    for (int r = 0; r < 4; ++r) {
      const int row = qr0 + lq * 4 + r;
      if (row < L_)
        ctxb[((size_t)b * L_ + row) * 768 + col] = f2b(accO[i][r]);
    }
  }
}

// ------- LayerNorm(A[bf16] + Bres[bf16]) -> bf16, vectorized (8 rows/block)
__global__ __launch_bounds__(256)
void ln8_kernel(const ushort* __restrict__ Ab, const ushort* __restrict__ Bres,
                const float* __restrict__ g, const float* __restrict__ beta,
                ushort* __restrict__ outb)
{
  const int tid = threadIdx.x;
  const int rr = tid >> 5;
  const int lane = tid & 31;
  const size_t row = (size_t)blockIdx.x * 8 + rr;
  const ushort* ap = Ab + row * U_;
  const ushort* bp = Bres + row * U_;
  float v[24];
  float s = 0.f, sq = 0.f;
#pragma unroll
  for (int t = 0; t < 3; ++t) {
    bf16x8 av = *(const bf16x8*)(ap + t * 256 + lane * 8);
    bf16x8 bv = *(const bf16x8*)(bp + t * 256 + lane * 8);
#pragma unroll
    for (int i = 0; i < 8; ++i) {
      float xv = b2f((ushort)av[i]) + b2f((ushort)bv[i]);
      v[t * 8 + i] = xv; s += xv; sq += xv * xv;
    }
  }
#pragma unroll
  for (int off = 16; off; off >>= 1) {
    s += __shfl_xor(s, off);
    sq += __shfl_xor(sq, off);
  }
  const float m = s * (1.f / 768.f);
  const float rstd = rsqrtf(sq * (1.f / 768.f) - m * m + 1e-5f);
  ushort* op = outb + row * U_;
#pragma unroll
  for (int t = 0; t < 3; ++t) {
    bf16x8 o;
#pragma unroll
    for (int i = 0; i < 8; ++i) {
      const int c = t * 256 + lane * 8 + i;
      o[i] = (short)f2b((v[t * 8 + i] - m) * rstd * g[c] + beta[c]);
    }
    *(bf16x8*)(op + t * 256 + lane * 8) = o;
  }
}

// ---- graph front: {RGCN gather -> fcat2[:,768:1024] | edge softmax} -------
__global__ __launch_bounds__(256)
void graphfront_kernel(const ushort* __restrict__ combo, ushort* __restrict__ fcat2,
                       const int* __restrict__ speaker, float* __restrict__ edge_norm)
{
  const int tid = threadIdx.x;
  if (blockIdx.x < N_ / 8) {
    const int n = blockIdx.x * 8 + (tid >> 5);
    const int lane = tid & 31;
    const int b = n / L_, k = n - b * L_;
    const int j0 = max(0, k - 10), j1 = min(L_ - 1, k + 10);
    const int spk = speaker[n];
    float inv[4];
    {
      int cn[4] = {0, 0, 0, 0};
      for (int j = j0; j <= j1; ++j)
        cn[speaker[b * L_ + j] * 2 + (j >= k ? 1 : 0)]++;
#pragma unroll
      for (int q = 0; q < 4; ++q) inv[q] = cn[q] ? 1.f / (float)cn[q] : 0.f;
    }
    float acc[8] = {};
    for (int j = j0; j <= j1; ++j) {
      const int spj = speaker[b * L_ + j];
      const int c = (j >= k) ? 1 : 0;
      const int et = (spj * 2 + spk) * 2 + c;
      const float w = inv[spj * 2 + c];
      bf16x8 v = *(const bf16x8*)&combo[(size_t)(b * L_ + j) * NC_ + 512 + et * 256 + lane * 8];
#pragma unroll
      for (int i = 0; i < 8; ++i) acc[i] = fmaf(b2f((ushort)v[i]), w, acc[i]);
    }
    bf16x8 rt = *(const bf16x8*)&combo[(size_t)n * NC_ + 2560 + lane * 8];
    bf16x8 o;
#pragma unroll
    for (int i = 0; i < 8; ++i) o[i] = (short)f2b(acc[i] + b2f((ushort)rt[i]));
    *(bf16x8*)&fcat2[(size_t)n * 1024 + 768 + lane * 8] = o;
  } else {
    const int bj = blockIdx.x - N_ / 8;
    const int b = bj / L_, j = bj - b * L_;
    const int k0 = max(0, j - 10), k1 = min(L_ - 1, j + 10);
    __shared__ float s[32];
    const int wave = tid >> 6, lane = tid & 63;
    float tr[8];
    {
      bf16x8 tv = *(const bf16x8*)&combo[(size_t)bj * NC_ + lane * 8];
#pragma unroll
      for (int i = 0; i < 8; ++i) tr[i] = b2f((ushort)tv[i]);
    }
    for (int k = k0 + wave; k <= k1; k += 4) {
      bf16x8 v = *(const bf16x8*)&fcat2[(size_t)(b * L_ + k) * 1024 + lane * 8];
      float sc = 0.f;
#pragma unroll
      for (int i = 0; i < 8; ++i) sc = fmaf(b2f((ushort)v[i]), tr[i], sc);
#pragma unroll
      for (int off = 32; off; off >>= 1) sc += __shfl_xor(sc, off);
      if (lane == 0) s[k - k0] = sc;
    }
    __syncthreads();
    if (tid == 0) {
      const int W = k1 - k0 + 1;
      float m = -1e30f;
      for (int t = 0; t < W; ++t) m = fmaxf(m, s[t]);
      float sum = 0.f;
      for (int t = 0; t < W; ++t) { float e = __expf(s[t] - m); s[t] = e; sum += e; }
      const float inv = 1.f / sum;
      const int base = b * EPB_ + edge_prefix(j);
      for (int t = 0; t < W; ++t) edge_norm[base + t] = s[t] * inv;
    }
  }
}

// -------- GraphConv gather: h1 (fcat2[:,768:1024]) -> agg (fcat2[:,512:768])
__global__ __launch_bounds__(256)
void gcn_gather2_kernel(const float* __restrict__ edge_norm,
                        ushort* __restrict__ fcat2)
{
  const int tid = threadIdx.x;
  const int n = blockIdx.x * 8 + (tid >> 5);
  const int lane = tid & 31;
  const int b = n / L_, k = n - b * L_;
  const int j0 = max(0, k - 10), j1 = min(L_ - 1, k + 10);
  float acc[8] = {};
  for (int j = j0; j <= j1; ++j) {
    const float w = edge_norm[b * EPB_ + edge_prefix(j) + (k - max(0, j - 10))];
    bf16x8 v = *(const bf16x8*)&fcat2[(size_t)(b * L_ + j) * 1024 + 768 + lane * 8];
#pragma unroll
    for (int i = 0; i < 8; ++i) acc[i] = fmaf(b2f((ushort)v[i]), w, acc[i]);
  }
  bf16x8 o;
#pragma unroll
  for (int i = 0; i < 8; ++i) o[i] = (short)f2b(acc[i]);
  *(bf16x8*)&fcat2[(size_t)n * 1024 + 512 + lane * 8] = o;
}

// ------------- final tiny GEMM: out = hid(bf16) @ clf2_w^T + clf2_b --------
__global__ __launch_bounds__(256)
void clf2_kernel(const ushort* __restrict__ hid, const float* __restrict__ w,
                 const float* __restrict__ bias, float* __restrict__ out)
{
  __shared__ float wsm[7 * H_];
  const int tid = threadIdx.x;
  for (int i = tid; i < 7 * H_; i += 256) wsm[i] = w[i];
  __syncthreads();
  const int idx = blockIdx.x * 256 + threadIdx.x;
  if (idx < N_ * 7) {
    const int n = idx / 7, t = idx - n * 7;
    const ushort* hp = hid + (size_t)n * H_;
    const float* wp = wsm + t * H_;
    float acc = bias[t];
    for (int d0 = 0; d0 < H_; d0 += 8) {
      bf16x8 v = *(const bf16x8*)(hp + d0);
#pragma unroll
      for (int i = 0; i < 8; ++i) acc = fmaf(b2f((ushort)v[i]), wp[d0 + i], acc);
    }
    out[idx] = acc;
  }
}

extern "C" void kernel_launch(void* const* d_in, const int* in_sizes, int n_in,
                              void* d_out, int out_size, void* d_ws, size_t ws_size,
                              hipStream_t stream)
{
  const float* x          = (const float*)d_in[0];
  const float* in_proj_w  = (const float*)d_in[1];
  const float* in_proj_b  = (const float*)d_in[2];
  const float* out_proj_w = (const float*)d_in[3];
  const float* out_proj_b = (const float*)d_in[4];
  const float* ln1_g      = (const float*)d_in[5];
  const float* ln1_b      = (const float*)d_in[6];
  const float* ff1_w      = (const float*)d_in[7];
  const float* ff1_b      = (const float*)d_in[8];
  const float* ff2_w      = (const float*)d_in[9];
  const float* ff2_b      = (const float*)d_in[10];
  const float* ln2_g      = (const float*)d_in[11];
  const float* ln2_b      = (const float*)d_in[12];
  const float* to_w       = (const float*)d_in[13];
  const float* to_b       = (const float*)d_in[14];
  const float* att_w      = (const float*)d_in[15];
  const float* rgcn_basis = (const float*)d_in[16];
  const float* rgcn_comp  = (const float*)d_in[17];
  const float* rgcn_root  = (const float*)d_in[18];
  const float* rgcn_bias  = (const float*)d_in[19];
  const float* gc_rel_w   = (const float*)d_in[20];
  const float* gc_rel_b   = (const float*)d_in[21];
  const float* gc_root_w  = (const float*)d_in[22];
  const float* clf1_w     = (const float*)d_in[23];
  const float* clf1_b     = (const float*)d_in[24];
  const float* clf2_w     = (const float*)d_in[25];
  const float* clf2_b     = (const float*)d_in[26];
  const int*   speaker    = (const int*)d_in[27];
  float* out = (float*)d_out;
  char* p = (char*)d_ws;

  // ---- workspace regions ----
  ushort* R1b    = (ushort*)p;
  p += (size_t)N_ * 2304 * 4;
  ushort* aprojB = (ushort*)p;
  ushort* ffoB   = aprojB;
  float*  en     = (float*)(p + (size_t)N_ * 512 * 4);
  p += (size_t)N_ * 768 * 4;
  ushort* vt    = (ushort*)p;
  ushort* hidB  = (ushort*)p;
  p += (size_t)N_ * 768 * 4;
  ushort* xb    = (ushort*)p;
  p += (size_t)N_ * 768 * 2;
  ushort* hb    = (ushort*)p;
  p += (size_t)N_ * 768 * 2;
  ushort* fcat2 = (ushort*)p;
  ushort* ctxb  = (ushort*)p;
  p += (size_t)N_ * 1024 * 2;
  ushort* in_projb = (ushort*)p; p += (size_t)2304 * 768 * 2;
  ushort* out_projb= (ushort*)p; p += (size_t)768 * 768 * 2;
  ushort* ff1b     = (ushort*)p; p += (size_t)2048 * 768 * 2;
  ushort* ff2b     = (ushort*)p; p += (size_t)768 * 2048 * 2;
  ushort* tob      = (ushort*)p; p += (size_t)512 * 768 * 2;
  ushort* combw    = (ushort*)p; p += (size_t)NC_ * 512 * 2;
  ushort* clf1b16  = (ushort*)p; p += (size_t)256 * 768 * 2;
  ushort* Wp       = (ushort*)p; p += (size_t)256 * 1024 * 2;
  ushort* grelrootT= (ushort*)p; p += (size_t)512 * 256 * 2;
  float*  bias_comb= (float*)p;  p += NC_ * 4;
  float*  bias2    = (float*)p;  p += 256 * 4;

  // ---- prep (1 dispatch) + Wcd GEMM ----
  PrepArgs pa;
  pa.cin[0] = x;          pa.cout[0] = xb;        pa.n4[0] = N_ * 768 / 4;
  pa.cin[1] = in_proj_w;  pa.cout[1] = in_projb;  pa.n4[1] = 2304 * 768 / 4;
  pa.cin[2] = out_proj_w; pa.cout[2] = out_projb; pa.n4[2] = 768 * 768 / 4;
  pa.cin[3] = ff1_w;      pa.cout[3] = ff1b;      pa.n4[3] = 2048 * 768 / 4;
  pa.cin[4] = ff2_w;      pa.cout[4] = ff2b;      pa.n4[4] = 768 * 2048 / 4;
  pa.cin[5] = to_w;       pa.cout[5] = tob;       pa.n4[5] = 512 * 768 / 4;
  pa.cin[6] = clf1_w;     pa.cout[6] = clf1b16;   pa.n4[6] = 256 * 768 / 4;
  pa.rb = rgcn_bias; pa.grel = gc_rel_w; pa.groot = gc_root_w;
  pa.clf1w = clf1_w; pa.clf1bias = clf1_b; pa.grelb = gc_rel_b;
  pa.attw = att_w; pa.basis = rgcn_basis; pa.comp = rgcn_comp; pa.root = rgcn_root;
  pa.bias_comb = bias_comb; pa.grelrootT = grelrootT; pa.Wp = Wp;
  pa.bias2 = bias2; pa.combw = combw;
  prep_kernel<<<dim3(768, 9), 256, 0, stream>>>(pa);
  // Wp[:,512:1024] = clf1[:,512:768] @ [gc_rel^T; gc_root^T]^T
  mgemm64_kernel<false, false><<<dim3(8, 2), 256, 0, stream>>>(
      clf1b16 + 512, grelrootT, nullptr, Wp + 512, 256, 768, 256, 1024);

  // ---- main pipeline ----
  // qkvb = bf16(x @ in_proj^T + b)      (64x128 tiles: 1980 blocks)
  mgemmW_kernel<true, false><<<dim3(18, 110), 256, 0, stream>>>(
      xb, in_projb, in_proj_b, R1b, 768, 768, 768, 2304);
  vtrans_kernel<<<dim3(24, 4, 64), 256, 0, stream>>>(R1b, vt);
  attnM_kernel<<<448, 256, 0, stream>>>(R1b, vt, ctxb);
  // aprojB = bf16(ctx @ out_proj^T + b)
  mgemm64_kernel<true, false><<<dim3(12, 55), 256, 0, stream>>>(
      ctxb, out_projb, out_proj_b, aprojB, 768, 768, 768, 768);
  ln8_kernel<<<N_ / 8, 256, 0, stream>>>(xb, aprojB, ln1_g, ln1_b, hb);
  // ff = relu(h @ ff1^T + b)            (64x128 tiles: 1760 blocks)
  mgemmW_kernel<true, true><<<dim3(16, 110), 256, 0, stream>>>(
      hb, ff1b, ff1_b, R1b, 768, 768, 768, 2048);
  // ffoB = bf16(ff @ ff2^T + b)
  mgemm64_kernel<true, false><<<dim3(12, 55), 256, 0, stream>>>(
      R1b, ff2b, ff2_b, ffoB, 2048, 2048, 2048, 768);
  ln8_kernel<<<N_ / 8, 256, 0, stream>>>(hb, ffoB, ln2_g, ln2_b, hb);
  // feats -> fcat2[:, 0:512]  (ldc = 1024)
  mgemm64_kernel<true, false><<<dim3(8, 55), 256, 0, stream>>>(
      hb, tob, to_b, fcat2, 768, 768, 768, 1024);
  // combo = bf16(feats @ [attw_t|wrel_t|root_t]^T + bias_comb)  (2420 blocks)
  mgemmW_kernel<true, false><<<dim3(22, 110), 256, 0, stream>>>(
      fcat2, combw, bias_comb, R1b, 512, 1024, 512, NC_);
  graphfront_kernel<<<N_ / 8 + N_, 256, 0, stream>>>(R1b, fcat2, speaker, en);
  gcn_gather2_kernel<<<N_ / 8, 256, 0, stream>>>(en, fcat2);
  // hid = relu([feats|agg|h1] @ [W1a|Wc|Wd]^T + bias2)   (K = 1024)
  mgemm64_kernel<true, true><<<dim3(4, 55), 256, 0, stream>>>(
      fcat2, Wp, bias2, hidB, 1024, 1024, 1024, 256);
  clf2_kernel<<<(N_ * 7 + 255) / 256, 256, 0, stream>>>(hidB, clf2_w, clf2_b, out);
}